// Round 15
// baseline (251.647 us; speedup 1.0000x reference)
//
#include <hip/hip_runtime.h>
#include <hip/hip_bf16.h>
#include <cmath>

#define B_    16
#define L_    2048
#define T_    32768   // B_*L_
#define DM_   128
#define DI_   256
#define DBC_  128     // XBC2 row stride: C stored at cols 64..127 (B not materialized)
#define DS_   64
#define HD_   64
#define NH_   4
#define NC_   32      // chunks per sequence (L_/64)

typedef __hip_bfloat16 bf16;
typedef __attribute__((ext_vector_type(8))) short short8;
typedef __attribute__((ext_vector_type(4))) float f32x4;

__device__ __forceinline__ float b2f(bf16 v) { return __bfloat162float(v); }
__device__ __forceinline__ bf16  f2b(float f) { return __float2bfloat16(f); }
__device__ __forceinline__ short f2bs(float f) { bf16 h = __float2bfloat16(f); return *reinterpret_cast<short*>(&h); }
__device__ __forceinline__ float bs2f(short s) { bf16 h = *reinterpret_cast<bf16*>(&s); return __bfloat162float(h); }
// fast transcendentals: v_exp_f32 / v_log_f32 / v_rcp_f32 (1-2 ulp, fine for bf16)
__device__ __forceinline__ float frcp_(float x) { return __builtin_amdgcn_rcpf(x); }
__device__ __forceinline__ float sigmoidf_(float x) { return frcp_(1.f + __expf(-x)); }
__device__ __forceinline__ float softplusf_(float x) { return (x > 20.f) ? x : __logf(1.f + __expf(x)); }
__device__ __forceinline__ float expneg_(float x) { return __expf(fminf(x, 0.f)); }

struct __align__(8) S4 { short a, b, c, d; };

#define NWI 82432   // 644*128
#define NWO 32768   // 128*256

// ---------------------------------------------------------------------------
// K0: one-time f32 -> bf16 conversion of Wi_f/b, Wo_f/b (weights only).
// ---------------------------------------------------------------------------
__global__ __launch_bounds__(256) void k_prep(
    const float* __restrict__ WiF, const float* __restrict__ WiB,
    const float* __restrict__ WoF, const float* __restrict__ WoB,
    bf16* __restrict__ WiFb, bf16* __restrict__ WiBb,
    bf16* __restrict__ WoFb, bf16* __restrict__ WoBb)
{
    const int gid = blockIdx.x * 256 + threadIdx.x;
    const int stride = gridDim.x * 256;
    for (int i = gid; i < NWI / 4; i += stride) {
        float4 v = ((const float4*)WiF)[i];
        S4 s = { f2bs(v.x), f2bs(v.y), f2bs(v.z), f2bs(v.w) };
        ((S4*)WiFb)[i] = s;
        v = ((const float4*)WiB)[i];
        S4 t = { f2bs(v.x), f2bs(v.y), f2bs(v.z), f2bs(v.w) };
        ((S4*)WiBb)[i] = t;
    }
    for (int i = gid; i < NWO / 4; i += stride) {
        float4 v = ((const float4*)WoF)[i];
        S4 s = { f2bs(v.x), f2bs(v.y), f2bs(v.z), f2bs(v.w) };
        ((S4*)WoFb)[i] = s;
        v = ((const float4*)WoB)[i];
        S4 t = { f2bs(v.x), f2bs(v.y), f2bs(v.z), f2bs(v.w) };
        ((S4*)WoBb)[i] = t;
    }
}

// ---------------------------------------------------------------------------
// K1 v4 (MFMA, FUSED in_proj + conv + silu + intra-chunk SSM):
// R14 change: ALL 4 heads' conv-X MFMAs + taps hoisted BEFORE the head loop
// (results in 16 S4 regs) -> xs is dead afterwards; its space aliases a
// second Xt buffer. Double-buffered Xt (Cs / xs-alias) -> 1 barrier per head
// (was 2). Total barriers 10 -> 7. Values bit-identical.
// grid (512, 2), block 256.
// ---------------------------------------------------------------------------
__global__ __launch_bounds__(256) void k_front_fused(
    const float* __restrict__ x, const bf16* __restrict__ WiFb, const bf16* __restrict__ WiBb,
    const float* __restrict__ cwF, const float* __restrict__ cbF,
    const float* __restrict__ cwB, const float* __restrict__ cbB,
    const float* __restrict__ dtbF, const float* __restrict__ dtbB,
    const float* __restrict__ AlF, const float* __restrict__ AlB,
    const float* __restrict__ DpF, const float* __restrict__ DpB,
    bf16* __restrict__ Z, bf16* __restrict__ XBC2, float* __restrict__ DTV,
    bf16* __restrict__ Y, bf16* __restrict__ ST, float* __restrict__ CDb)
{
    const int tid  = threadIdx.x;
    const int wave = tid >> 6, lane = tid & 63;
    const int ln15 = lane & 15, q = lane >> 4;
    const int ch16 = 16 * wave + ln15;   // this thread's channel within a 64-ch tile
    const int dir  = blockIdx.y;
    const bf16* Wi = dir ? WiBb : WiFb;
    const int t0 = blockIdx.x * 64;
    const int batch = t0 >> 11, l0 = t0 & (L_ - 1);
    const int cc = l0 >> 6;   // chunk index
    const size_t rowbase = (size_t)dir * T_ + t0;
    const float* Al = dir ? AlB : AlF;
    const float* Dp = dir ? DpB : DpF;
    const float* cw = dir ? cwB : cwF;
    const float* cb = dir ? cbB : cbF;

    __shared__ __align__(16) short xs[80][136];    // tokens; aliased as Xt2 in phase 5
    __shared__ __align__(16) short Bs[64][72];     // B tile; later Ms / Yd stage
    __shared__ __align__(16) short Cs[64][72];     // C tile; later Xt (even heads)
    __shared__ __align__(16) short Bt[64][72];     // B^T (written direct in phase 3)
    __shared__ float dts2[NH_][64];                // dt per (head, token)
    __shared__ float Acs4[NH_][64];
    __shared__ float decs4[NH_][64];

    // ---- phase 0: stage x ----
    for (int u = tid; u < 1280; u += 256) {
        int r = u >> 4, g = u & 15;
        int l = l0 - 16 + r;
        short8 v = {0, 0, 0, 0, 0, 0, 0, 0};
        if (l >= 0) {
            int sl = dir ? (L_ - 1 - l) : l;
            const float* px = x + ((size_t)batch * L_ + sl) * DM_ + g * 8;
            float4 v0 = *(const float4*)px;
            float4 v1 = *(const float4*)(px + 4);
            v = (short8){ f2bs(v0.x), f2bs(v0.y), f2bs(v0.z), f2bs(v0.w),
                          f2bs(v1.x), f2bs(v1.y), f2bs(v1.z), f2bs(v1.w) };
        }
        *(short8*)&xs[r][g * 8] = v;
    }
    __syncthreads();   // B0: xs ready

    // ---- phase 1: dt (wave w = 16-token strip w) -> dts2 + DTV ----
    {
        short8 bfr[4];
#pragma unroll
        for (int ks = 0; ks < 4; ++ks) {
            short8 v = {0, 0, 0, 0, 0, 0, 0, 0};
            if (ln15 < 4) v = *(const short8*)(Wi + (size_t)(640 + ln15) * DM_ + ks * 32 + q * 8);
            bfr[ks] = v;
        }
        const float* dtb = dir ? dtbB : dtbF;
        f32x4 acc = (f32x4){0.f, 0.f, 0.f, 0.f};
#pragma unroll
        for (int ks = 0; ks < 4; ++ks) {
            short8 afr = *(const short8*)&xs[16 + 16 * wave + ln15][ks * 32 + q * 8];
            acc = __builtin_amdgcn_mfma_f32_16x16x32_bf16(afr, bfr[ks], acc, 0, 0, 0);
        }
        if (ln15 < 4) {
            float bias = dtb[ln15];
#pragma unroll
            for (int rg = 0; rg < 4; ++rg) {
                int l = 16 * wave + 4 * q + rg;
                float dv = softplusf_(acc[rg] + bias);
                DTV[(rowbase + l) * NH_ + ln15] = dv;
                dts2[ln15][l] = dv;
            }
        }
    }

    // ---- phase 2: Z tiles (4), barrier-free ----
#pragma unroll
    for (int zt = 0; zt < 4; ++zt) {
        const int c0 = zt * 64;
        short8 wf[4];
#pragma unroll
        for (int ks = 0; ks < 4; ++ks)
            wf[ks] = *(const short8*)(Wi + (size_t)(c0 + ch16) * DM_ + ks * 32 + q * 8);
#pragma unroll
        for (int ct = 0; ct < 4; ++ct) {
            f32x4 acc = (f32x4){0.f, 0.f, 0.f, 0.f};
#pragma unroll
            for (int ks = 0; ks < 4; ++ks) {
                short8 xf = *(const short8*)&xs[16 + 16 * ct + ln15][ks * 32 + q * 8];
                acc = __builtin_amdgcn_mfma_f32_16x16x32_bf16(wf[ks], xf, acc, 0, 0, 0);
            }
            S4 s = { f2bs(acc[0]), f2bs(acc[1]), f2bs(acc[2]), f2bs(acc[3]) };
            *(S4*)(Z + (rowbase + 16 * ct + ln15) * DI_ + c0 + 16 * wave + 4 * q) = s;
        }
    }

    // ---- phase 3: B and C conv tiles, in-register taps, no barriers ----
    short8 bcur[4], bnxt[4];
#pragma unroll
    for (int ks = 0; ks < 4; ++ks)
        bcur[ks] = *(const short8*)(Wi + (size_t)(512 + ch16) * DM_ + ks * 32 + q * 8);

    for (int it = 0; it < 2; ++it) {   // it=0: B (Wi rows 512+), it=1: C (576+)
        f32x4 acc[5];
#pragma unroll
        for (int mt = 0; mt < 5; ++mt) acc[mt] = (f32x4){0.f, 0.f, 0.f, 0.f};
#pragma unroll
        for (int ks = 0; ks < 4; ++ks)
#pragma unroll
            for (int mt = 0; mt < 5; ++mt) {
                short8 afr = *(const short8*)&xs[16 * mt + ln15][ks * 32 + q * 8];
                acc[mt] = __builtin_amdgcn_mfma_f32_16x16x32_bf16(afr, bcur[ks], acc[mt], 0, 0, 0);
            }
        const int rnext = it ? 256 : 576;   // B -> C -> X0
#pragma unroll
        for (int ks = 0; ks < 4; ++ks)
            bnxt[ks] = *(const short8*)(Wi + (size_t)(rnext + ch16) * DM_ + ks * 32 + q * 8);
        const int gch = (it ? 320 : 256) + ch16;
        float wb = cb[gch], wv[4];
#pragma unroll
        for (int k = 0; k < 4; ++k) wv[k] = cw[gch * 4 + k];
#pragma unroll
        for (int mt = 1; mt <= 4; ++mt) {
            float p[3];
#pragma unroll
            for (int j = 0; j < 3; ++j) {
                float up = __shfl_up(acc[mt][j + 1], 16);
                float pw = __shfl(acc[mt - 1][j + 1], ln15 + 48);
                p[j] = (q == 0) ? pw : up;
            }
            float P[7] = { p[0], p[1], p[2], acc[mt][0], acc[mt][1], acc[mt][2], acc[mt][3] };
            short o[4];
#pragma unroll
            for (int rg = 0; rg < 4; ++rg) {
                float s = wb;
#pragma unroll
                for (int k = 0; k < 4; ++k) s += P[rg + k] * wv[k];
                s = s * sigmoidf_(s);
                o[rg] = f2bs(s);
                int row = 16 * (mt - 1) + 4 * q + rg;
                if (it == 0) Bs[row][ch16] = o[rg];
                else         Cs[row][ch16] = o[rg];
            }
            if (it == 0) {
                // channel-major B slice -> Bt direct (no phase-4 transpose)
                *(S4*)&Bt[ch16][16 * (mt - 1) + 4 * q] = (S4){ o[0], o[1], o[2], o[3] };
            }
        }
#pragma unroll
        for (int ks = 0; ks < 4; ++ks) bcur[ks] = bnxt[ks];
    }
    __syncthreads();   // B1: Bs, Cs, Bt, dts2 ready

    // ---- phase 4: scans, C global store, G = C B^T ----
    {
        const int h = wave, l = lane;
        const float Ah = -__expf(Al[h]);
        float dt = dts2[h][l];
        float s = dt * Ah;
#pragma unroll
        for (int off = 1; off < 64; off <<= 1) {
            float t2 = __shfl_up(s, off);
            if (l >= off) s += t2;
        }
        Acs4[h][l] = s;
        float alast = __shfl(s, 63);
        decs4[h][l] = expneg_(alast - s);
        if (l == 0) CDb[(((size_t)dir * B_ + batch) * NH_ + h) * NC_ + cc] = expneg_(alast);
    }
    // coalesced C -> XBC2 global (tail consumes it)
    for (int u = tid; u < 512; u += 256) {
        int r = u >> 3, g = u & 7;
        *(short8*)(XBC2 + (rowbase + r) * DBC_ + 64 + g * 8) = *(const short8*)&Cs[r][g * 8];
    }
    // G = C B^T once (head-independent); A-frag = own-wave Cs rows
    f32x4 a1[4];
#pragma unroll
    for (int ct = 0; ct < 4; ++ct) a1[ct] = (f32x4){0.f, 0.f, 0.f, 0.f};
#pragma unroll
    for (int ks = 0; ks < 2; ++ks) {
        short8 afr = *(const short8*)&Cs[16 * wave + ln15][ks * 32 + q * 8];
#pragma unroll
        for (int ct = 0; ct < 4; ++ct) {
            short8 bfr = *(const short8*)&Bs[16 * ct + ln15][ks * 32 + q * 8];
            a1[ct] = __builtin_amdgcn_mfma_f32_16x16x32_bf16(afr, bfr, a1[ct], 0, 0, 0);
        }
    }

    // ---- phase 5a: ALL heads' conv-X -> registers (xs dead afterwards) ----
    S4 xvh[NH_][4];   // [head][mt] token-major slices, dt folded
#pragma unroll
    for (int h = 0; h < NH_; ++h) {
        f32x4 acc[5];
#pragma unroll
        for (int mt = 0; mt < 5; ++mt) acc[mt] = (f32x4){0.f, 0.f, 0.f, 0.f};
#pragma unroll
        for (int ks = 0; ks < 4; ++ks)
#pragma unroll
            for (int mt = 0; mt < 5; ++mt) {
                short8 afr = *(const short8*)&xs[16 * mt + ln15][ks * 32 + q * 8];
                acc[mt] = __builtin_amdgcn_mfma_f32_16x16x32_bf16(afr, bcur[ks], acc[mt], 0, 0, 0);
            }
        if (h < NH_ - 1) {
#pragma unroll
            for (int ks = 0; ks < 4; ++ks)
                bnxt[ks] = *(const short8*)(Wi + (size_t)(320 + 64 * h + ch16) * DM_
                                            + ks * 32 + q * 8);
        }
        const int gch = 64 * h + ch16;
        float wb = cb[gch], wv[4];
#pragma unroll
        for (int k = 0; k < 4; ++k) wv[k] = cw[gch * 4 + k];
#pragma unroll
        for (int mt = 1; mt <= 4; ++mt) {
            float p[3];
#pragma unroll
            for (int j = 0; j < 3; ++j) {
                float up = __shfl_up(acc[mt][j + 1], 16);
                float pw = __shfl(acc[mt - 1][j + 1], ln15 + 48);
                p[j] = (q == 0) ? pw : up;
            }
            float P[7] = { p[0], p[1], p[2], acc[mt][0], acc[mt][1], acc[mt][2], acc[mt][3] };
            short o[4];
#pragma unroll
            for (int rg = 0; rg < 4; ++rg) {
                float s = wb;
#pragma unroll
                for (int k = 0; k < 4; ++k) s += P[rg + k] * wv[k];
                s = s * sigmoidf_(s);
                o[rg] = f2bs(s * dts2[h][16 * (mt - 1) + 4 * q + rg]);
            }
            xvh[h][mt - 1] = (S4){ o[0], o[1], o[2], o[3] };
        }
#pragma unroll
        for (int ks = 0; ks < 4; ++ks) bcur[ks] = bnxt[ks];
    }
    __syncthreads();   // B2: phase-4 Cs/Bs readers done; xs reads done block-wide

    // second Xt buffer aliased onto dead xs space (row stride 72, 16B-aligned)
    short (*Xt2)[72] = reinterpret_cast<short (*)[72]>(&xs[0][0]);

    // ---- phase 5b: per-head, double-buffered Xt, ONE barrier per head ----
#pragma unroll
    for (int h = 0; h < NH_; ++h) {
        const float Dh = Dp[h];
        short (*Xt)[72] = (h & 1) ? Xt2 : Cs;
        // write Xt: row ch16 (wave-private), cols = tokens, S4 each
#pragma unroll
        for (int mt = 0; mt < 4; ++mt)
            *(S4*)&Xt[ch16][16 * mt + 4 * q] = xvh[h][mt];
        // mask+decay from hoisted a1 -> Ms (=Bs, own-wave rows)
#pragma unroll
        for (int ct = 0; ct < 4; ++ct)
#pragma unroll
            for (int rg = 0; rg < 4; ++rg) {
                int l = 16 * wave + 4 * q + rg, s = 16 * ct + ln15;
                float m = (s <= l) ? a1[ct][rg] * expneg_(Acs4[h][l] - Acs4[h][s]) : 0.f;
                Bs[l][s] = f2bs(m);
            }
        __syncthreads();   // P_h: Xt published (Ms is wave-private)

        // step 2: Yd = M @ Xdt
        f32x4 a2[4];
#pragma unroll
        for (int ct = 0; ct < 4; ++ct) a2[ct] = (f32x4){0.f, 0.f, 0.f, 0.f};
#pragma unroll
        for (int ks = 0; ks < 2; ++ks) {
            short8 afr = *(const short8*)&Bs[16 * wave + ln15][ks * 32 + q * 8];
#pragma unroll
            for (int ct = 0; ct < 4; ++ct) {
                short8 bfr = *(const short8*)&Xt[16 * ct + ln15][ks * 32 + q * 8];
                a2[ct] = __builtin_amdgcn_mfma_f32_16x16x32_bf16(afr, bfr, a2[ct], 0, 0, 0);
            }
        }
        // Yd tile into Bs (own rows), then coalesced 16 B/lane store
        float rdt[4];
#pragma unroll
        for (int rg = 0; rg < 4; ++rg) rdt[rg] = frcp_(dts2[h][16 * wave + 4 * q + rg]);
#pragma unroll
        for (int ct = 0; ct < 4; ++ct)
#pragma unroll
            for (int rg = 0; rg < 4; ++rg) {
                int l = 16 * wave + 4 * q + rg, p = 16 * ct + ln15;
                float xraw = bs2f(Xt[p][l]) * rdt[rg];
                Bs[l][p] = f2bs(a2[ct][rg] + Dh * xraw);
            }
#pragma unroll
        for (int i = 0; i < 2; ++i) {
            int row = 16 * wave + (lane >> 3) + 8 * i;
            int g = (lane & 7) * 8;
            short8 v = *(const short8*)&Bs[row][g];
            *(short8*)(Y + (rowbase + row) * DI_ + h * HD_ + g) = v;
        }
        // step 3: st[p][n] = sum_l (Xdt^T * dec)[p][l] * B^T[n][l]
        f32x4 a3[4];
#pragma unroll
        for (int ct = 0; ct < 4; ++ct) a3[ct] = (f32x4){0.f, 0.f, 0.f, 0.f};
#pragma unroll
        for (int ks = 0; ks < 2; ++ks) {
            short8 af = *(const short8*)&Xt[16 * wave + ln15][ks * 32 + q * 8];
            short8 afs;
#pragma unroll
            for (int j = 0; j < 8; ++j) {
                int l2 = ks * 32 + q * 8 + j;
                afs[j] = f2bs(bs2f(af[j]) * decs4[h][l2]);
            }
#pragma unroll
            for (int ct = 0; ct < 4; ++ct) {
                short8 bfr = *(const short8*)&Bt[16 * ct + ln15][ks * 32 + q * 8];
                a3[ct] = __builtin_amdgcn_mfma_f32_16x16x32_bf16(afs, bfr, a3[ct], 0, 0, 0);
            }
        }
        size_t sb = ((((size_t)dir * B_ + batch) * NC_ + cc) * NH_ + h) * 4096;
#pragma unroll
        for (int ct = 0; ct < 4; ++ct)
#pragma unroll
            for (int rg = 0; rg < 4; ++rg) {
                int p = 16 * wave + 4 * q + rg, n = 16 * ct + ln15;
                ST[sb + p * 64 + n] = f2b(a3[ct][rg]);
            }
    }
}

// ---------------------------------------------------------------------------
// K3 v3: inter-chunk scan, in place, 4 elem/thread (S4).
// (unchanged — cdr preload + 8-deep prefetch, fully unrolled)
// grid (256, 2), block 256.
// ---------------------------------------------------------------------------
__global__ __launch_bounds__(256) void k_scan(bf16* __restrict__ ST, const float* __restrict__ CDb)
{
    const int tid = threadIdx.x;
    const int dir = blockIdx.y;
    const int bx = blockIdx.x;                 // b*16 + h*4 + sg
    const int b = bx >> 4, h = (bx >> 2) & 3, sg = bx & 3;
    const size_t cdbase = (((size_t)dir * B_ + b) * NH_ + h) * NC_;
    const size_t base0 = (((size_t)dir * B_ + b) * NC_ * NH_ + h) * 4096
                       + (size_t)(sg * 256 + tid) * 4;
    const size_t cstride = (size_t)NH_ * 4096;   // chunk stride in elements

    // decay factors fully preloaded -> off the serial carry chain
    float cdr[32];
#pragma unroll
    for (int i = 0; i < 8; ++i) {
        float4 v = *(const float4*)(CDb + cdbase + i * 4);
        cdr[i * 4 + 0] = v.x; cdr[i * 4 + 1] = v.y;
        cdr[i * 4 + 2] = v.z; cdr[i * 4 + 3] = v.w;
    }
    // 8-deep ST prefetch
    S4 buf[8];
#pragma unroll
    for (int i = 0; i < 8; ++i)
        buf[i] = *(const S4*)(ST + base0 + (size_t)i * cstride);

    float carry[4] = {0.f, 0.f, 0.f, 0.f};
#pragma unroll
    for (int c = 0; c < NC_; ++c) {
        S4 cur = buf[c & 7];
        if (c + 8 < NC_)
            buf[c & 7] = *(const S4*)(ST + base0 + (size_t)(c + 8) * cstride);
        S4 st4 = { f2bs(carry[0]), f2bs(carry[1]), f2bs(carry[2]), f2bs(carry[3]) };
        *(S4*)(ST + base0 + (size_t)c * cstride) = st4;
        float cd = cdr[c];
        carry[0] = carry[0] * cd + bs2f(cur.a);
        carry[1] = carry[1] * cd + bs2f(cur.b);
        carry[2] = carry[2] * cd + bs2f(cur.c);
        carry[3] = carry[3] * cd + bs2f(cur.d);
    }
}

// ---------------------------------------------------------------------------
// K4 v5 (MFMA, FUSED offdiag + gate/RMSNorm + out-projection, 8 waves):
// (unchanged — issue-early ST prefetch + LDS-staged Ps2, C in regs)
// grid: (32, 16), block 512.
// ---------------------------------------------------------------------------
__global__ __launch_bounds__(512) void k_tail_fused(
    const bf16* __restrict__ XBC2, const float* __restrict__ DTV,
    const float* __restrict__ AlF, const float* __restrict__ AlB,
    const bf16* __restrict__ ST, const bf16* __restrict__ Z,
    const float* __restrict__ nwF, const float* __restrict__ nwB,
    const bf16* __restrict__ Y,
    const bf16* __restrict__ WoFb, const bf16* __restrict__ WoBb,
    float* __restrict__ out)
{
    const int tid = threadIdx.x;
    const int wave = tid >> 6, lane = tid & 63;
    const int ln15 = lane & 15, q = lane >> 4;
    const int grp = wave >> 2, strip = wave & 3;   // grp: head-pair member / N-half
    const int c = blockIdx.x, b = blockIdx.y;
    const int pt0 = b * L_ + c * 64;               // physical token base

    __shared__ __align__(16) short Ps2[2][64][72];
    __shared__ __align__(16) short Yz[64][264];
    __shared__ float eA[NH_][64];

    f32x4 acc[4];
#pragma unroll
    for (int ct = 0; ct < 4; ++ct) acc[ct] = (f32x4){0.f, 0.f, 0.f, 0.f};

    for (int d = 0; d < 2; ++d) {
        const int cd = d ? (NC_ - 1 - c) : c;
        const size_t rowbase = (size_t)d * T_ + (size_t)b * L_ + cd * 64;
        const float* Al = d ? AlB : AlF;
        const float* nw = d ? nwB : nwF;
        const bf16* Wo = d ? WoBb : WoFb;

        if (d) __syncthreads();   // dir0's Yz/Ps2 reads fully done before restage

        // ---- T14 issue-early: all 4 heads' ST fragments (4 short8/thread) ----
        short8 stq[4];
        const size_t sbase = ((((size_t)d * B_ + b) * NC_ + cd) * NH_) * 4096;
#pragma unroll
        for (int i = 0; i < 4; ++i) {
            int u = tid + 512 * i;
            int hh = u >> 9, r = (u >> 3) & 63, g = u & 7;
            stq[i] = *(const short8*)(ST + sbase + (size_t)hh * 4096 + r * 64 + g * 8);
        }

        // decay prefixes: waves 0-3, head = wave
        if (wave < NH_) {
            float A = -__expf(Al[wave]);
            float s = DTV[(rowbase + lane) * NH_ + wave] * A;
#pragma unroll
            for (int off = 1; off < 64; off <<= 1) {
                float t2 = __shfl_up(s, off);
                if (lane >= off) s += t2;
            }
            eA[wave][lane] = expneg_(s);
        }
        // stage Yd: 2048 short8, 4 per thread
#pragma unroll
        for (int i = 0; i < 4; ++i) {
            int u = tid + 512 * i;
            int r = u >> 5, g = u & 31;
            *(short8*)&Yz[r][g * 8] = *(const short8*)(Y + (rowbase + r) * DI_ + g * 8);
        }
        // C fragment in regs (A-operand), reused for both heads of this wave
        short8 afr[2];
#pragma unroll
        for (int ks = 0; ks < 2; ++ks)
            afr[ks] = *(const short8*)(XBC2 + (rowbase + 16 * strip + ln15) * DBC_
                                       + 64 + ks * 32 + q * 8);
        // write pr=0 Ps2 (heads 0,1) from prefetched regs — covered by B1
#pragma unroll
        for (int i = 0; i < 2; ++i) {
            int u = tid + 512 * i;
            int hh = u >> 9, r = (u >> 3) & 63, g = u & 7;
            *(short8*)&Ps2[hh][r][g * 8] = stq[i];
        }
        __syncthreads();   // B1: Yz, eA, Ps2(h0,h1) ready

        // head pairs: group 0-3 -> head 2*pr, group 4-7 -> head 2*pr+1
        for (int pr = 0; pr < 2; ++pr) {
            const int h = 2 * pr + grp;
            f32x4 a2[4];
#pragma unroll
            for (int ct = 0; ct < 4; ++ct) a2[ct] = (f32x4){0.f, 0.f, 0.f, 0.f};
#pragma unroll
            for (int ks = 0; ks < 2; ++ks)
#pragma unroll
                for (int ct = 0; ct < 4; ++ct) {
                    short8 bfr = *(const short8*)&Ps2[grp][16 * ct + ln15][ks * 32 + q * 8];
                    a2[ct] = __builtin_amdgcn_mfma_f32_16x16x32_bf16(afr[ks], bfr, a2[ct], 0, 0, 0);
                }
#pragma unroll
            for (int ct = 0; ct < 4; ++ct)
#pragma unroll
                for (int rg = 0; rg < 4; ++rg) {
                    int l = 16 * strip + 4 * q + rg, p = 16 * ct + ln15;
                    float yv = bs2f(Yz[l][h * 64 + p]) + a2[ct][rg] * eA[h][l];
                    Yz[l][h * 64 + p] = f2bs(yv);   // disjoint (l, h-cols) per wave
                }
            if (pr == 0) {
                __syncthreads();   // B2: pr0 Ps2 consumers done
                // write pr=1 Ps2 (heads 2,3) from prefetched regs
#pragma unroll
                for (int i = 0; i < 2; ++i) {
                    int u = tid + 512 * (i + 2);
                    int hh = (u >> 9) - 2, r = (u >> 3) & 63, g = u & 7;
                    *(short8*)&Ps2[hh][r][g * 8] = stq[i + 2];
                }
                __syncthreads();   // B3: pr1 Ps2 ready
            }
        }
        __syncthreads();   // B4: all Yz head-updates visible

        // gate + RMSNorm: wave rows 8*wave .. 8*wave+7 (wave-private)
        float nwv[4];
#pragma unroll
        for (int j = 0; j < 4; ++j) nwv[j] = nw[lane * 4 + j];
#pragma unroll
        for (int rr = 0; rr < 8; ++rr) {
            int row = 8 * wave + rr;
            S4 zv4 = *(const S4*)(Z + (rowbase + row) * DI_ + lane * 4);
            short zr[4] = { zv4.a, zv4.b, zv4.c, zv4.d };
            float v[4]; float ss = 0.f;
#pragma unroll
            for (int j = 0; j < 4; ++j) {
                float yv = bs2f(Yz[row][lane * 4 + j]);
                float zf = bs2f(zr[j]);
                v[j] = yv * zf * sigmoidf_(zf);
                ss += v[j] * v[j];
            }
#pragma unroll
            for (int off = 1; off < 64; off <<= 1) ss += __shfl_xor(ss, off);
            float rn = rsqrtf(ss * (1.f / 256.f) + 1e-5f);
#pragma unroll
            for (int j = 0; j < 4; ++j)
                Yz[row][lane * 4 + j] = f2bs(v[j] * rn * nwv[j]);
        }
        __syncthreads();   // B5: final Yz visible to all waves

        // out-projection accumulate; wave = (strip, Nhalf=grp); dir1 row-reversed
        const int prow = 16 * strip + ln15;
        const int lr = d ? 63 - prow : prow;
        short8 wf[4], wfn[4];
#pragma unroll
        for (int ct = 0; ct < 4; ++ct)
            wf[ct] = *(const short8*)(Wo + (size_t)(16 * (4 * grp + ct) + ln15) * DI_ + q * 8);
#pragma unroll
        for (int it = 0; it < 8; ++it) {
            const int k0 = (it >> 1) * 64 + (it & 1) * 32;
            if (it < 7) {
                const int k0n = ((it + 1) >> 1) * 64 + ((it + 1) & 1) * 32;
#pragma unroll
                for (int ct = 0; ct < 4; ++ct)
                    wfn[ct] = *(const short8*)(Wo + (size_t)(16 * (4 * grp + ct) + ln15) * DI_
                                               + k0n + q * 8);
            }
            short8 afr2 = *(const short8*)&Yz[lr][k0 + q * 8];
#pragma unroll
            for (int ct = 0; ct < 4; ++ct)
                acc[ct] = __builtin_amdgcn_mfma_f32_16x16x32_bf16(afr2, wf[ct], acc[ct], 0, 0, 0);
#pragma unroll
            for (int ct = 0; ct < 4; ++ct) wf[ct] = wfn[ct];
        }
    }

    // write out (f32), both dirs accumulated
#pragma unroll
    for (int ct = 0; ct < 4; ++ct)
#pragma unroll
        for (int rg = 0; rg < 4; ++rg) {
            int row = 16 * strip + 4 * q + rg, col = 16 * (4 * grp + ct) + ln15;
            out[((size_t)(pt0 + row)) * DM_ + col] = acc[ct][rg];
        }
}

// ---------------------------------------------------------------------------
extern "C" void kernel_launch(void* const* d_in, const int* in_sizes, int n_in,
                              void* d_out, int out_size, void* d_ws, size_t ws_size,
                              hipStream_t stream)
{
    const float* x    = (const float*)d_in[0];
    const float* WiF  = (const float*)d_in[1];
    const float* cwF  = (const float*)d_in[2];
    const float* cbF  = (const float*)d_in[3];
    const float* dtbF = (const float*)d_in[4];
    const float* AlF  = (const float*)d_in[5];
    const float* DpF  = (const float*)d_in[6];
    const float* nwF  = (const float*)d_in[7];
    const float* WoF  = (const float*)d_in[8];
    const float* WiB  = (const float*)d_in[9];
    const float* cwB  = (const float*)d_in[10];
    const float* cbB  = (const float*)d_in[11];
    const float* dtbB = (const float*)d_in[12];
    const float* AlB  = (const float*)d_in[13];
    const float* DpB  = (const float*)d_in[14];
    const float* nwB  = (const float*)d_in[15];
    const float* WoB  = (const float*)d_in[16];

    const size_t nZ    = (size_t)2 * T_ * DI_;       // bf16
    const size_t nXBC2 = (size_t)2 * T_ * DBC_;      // bf16 (C only, stride 128)
    const size_t nY    = (size_t)2 * T_ * DI_;       // bf16 (Yd)
    const size_t nST   = (size_t)2 * B_ * NC_ * NH_ * HD_ * DS_;  // bf16
    const size_t nWb   = (size_t)2 * NWI + 2 * NWO;  // bf16 weight copies
    const size_t nDTV  = (size_t)2 * T_ * NH_;       // f32
    const size_t nCD   = (size_t)2 * B_ * NH_ * NC_; // f32
    const size_t need = (nZ + nXBC2 + nY + nST + nWb) * sizeof(bf16)
                      + (nDTV + nCD) * sizeof(float);
    if (ws_size < need) return;

    char* p = (char*)d_ws;
    bf16* Z    = (bf16*)p;            p += nZ * sizeof(bf16);
    bf16* XBC2 = (bf16*)p;            p += nXBC2 * sizeof(bf16);
    bf16* Yb   = (bf16*)p;            p += nY * sizeof(bf16);
    bf16* ST   = (bf16*)p;            p += nST * sizeof(bf16);
    bf16* WiFb = (bf16*)p;            p += (size_t)NWI * sizeof(bf16);
    bf16* WiBb = (bf16*)p;            p += (size_t)NWI * sizeof(bf16);
    bf16* WoFb = (bf16*)p;            p += (size_t)NWO * sizeof(bf16);
    bf16* WoBb = (bf16*)p;            p += (size_t)NWO * sizeof(bf16);
    float* DTV = (float*)p;           p += nDTV * sizeof(float);
    float* CDb = (float*)p;

    k_prep<<<128, 256, 0, stream>>>(WiF, WiB, WoF, WoB, WiFb, WiBb, WoFb, WoBb);
    k_front_fused<<<dim3(512, 2), 256, 0, stream>>>(x, WiFb, WiBb, cwF, cbF, cwB, cbB,
                                                    dtbF, dtbB, AlF, AlB, DpF, DpB,
                                                    Z, XBC2, DTV, Yb, ST, CDb);
    k_scan<<<dim3(256, 2), 256, 0, stream>>>(ST, CDb);
    k_tail_fused<<<dim3(NC_, B_), 512, 0, stream>>>(XBC2, DTV, AlF, AlB, ST, Z,
                                                    nwF, nwB, Yb, WoFb, WoBb, (float*)d_out);
}

// Round 16
// 224.522 us; speedup vs baseline: 1.1208x; 1.1208x over previous
//
#include <hip/hip_runtime.h>
#include <hip/hip_bf16.h>
#include <cmath>

#define B_    16
#define L_    2048
#define T_    32768   // B_*L_
#define DM_   128
#define DI_   256
#define DBC_  128     // XBC2 row stride: C stored at cols 64..127 (B not materialized)
#define DS_   64
#define HD_   64
#define NH_   4
#define NC_   32      // chunks per sequence (L_/64)

typedef __hip_bfloat16 bf16;
typedef __attribute__((ext_vector_type(8))) short short8;
typedef __attribute__((ext_vector_type(4))) float f32x4;

__device__ __forceinline__ float b2f(bf16 v) { return __bfloat162float(v); }
__device__ __forceinline__ bf16  f2b(float f) { return __float2bfloat16(f); }
__device__ __forceinline__ short f2bs(float f) { bf16 h = __float2bfloat16(f); return *reinterpret_cast<short*>(&h); }
__device__ __forceinline__ float bs2f(short s) { bf16 h = *reinterpret_cast<bf16*>(&s); return __bfloat162float(h); }
// fast transcendentals: v_exp_f32 / v_log_f32 / v_rcp_f32 (1-2 ulp, fine for bf16)
__device__ __forceinline__ float frcp_(float x) { return __builtin_amdgcn_rcpf(x); }
__device__ __forceinline__ float sigmoidf_(float x) { return frcp_(1.f + __expf(-x)); }
__device__ __forceinline__ float softplusf_(float x) { return (x > 20.f) ? x : __logf(1.f + __expf(x)); }
__device__ __forceinline__ float expneg_(float x) { return __expf(fminf(x, 0.f)); }

struct __align__(8) S4 { short a, b, c, d; };

#define NWI 82432   // 644*128
#define NWO 32768   // 128*256

// ---------------------------------------------------------------------------
// K0: one-time f32 -> bf16 conversion of Wi_f/b, Wo_f/b (weights only).
// ---------------------------------------------------------------------------
__global__ __launch_bounds__(256) void k_prep(
    const float* __restrict__ WiF, const float* __restrict__ WiB,
    const float* __restrict__ WoF, const float* __restrict__ WoB,
    bf16* __restrict__ WiFb, bf16* __restrict__ WiBb,
    bf16* __restrict__ WoFb, bf16* __restrict__ WoBb)
{
    const int gid = blockIdx.x * 256 + threadIdx.x;
    const int stride = gridDim.x * 256;
    for (int i = gid; i < NWI / 4; i += stride) {
        float4 v = ((const float4*)WiF)[i];
        S4 s = { f2bs(v.x), f2bs(v.y), f2bs(v.z), f2bs(v.w) };
        ((S4*)WiFb)[i] = s;
        v = ((const float4*)WiB)[i];
        S4 t = { f2bs(v.x), f2bs(v.y), f2bs(v.z), f2bs(v.w) };
        ((S4*)WiBb)[i] = t;
    }
    for (int i = gid; i < NWO / 4; i += stride) {
        float4 v = ((const float4*)WoF)[i];
        S4 s = { f2bs(v.x), f2bs(v.y), f2bs(v.z), f2bs(v.w) };
        ((S4*)WoFb)[i] = s;
        v = ((const float4*)WoB)[i];
        S4 t = { f2bs(v.x), f2bs(v.y), f2bs(v.z), f2bs(v.w) };
        ((S4*)WoBb)[i] = t;
    }
}

// ---------------------------------------------------------------------------
// K1 v3 (MFMA, FUSED in_proj + conv + silu + intra-chunk SSM):
// (REVERT to R13 build: VGPR-68 version. R14's all-heads conv hoist pushed
// VGPR to 144 -> occupancy 23.7% -> 10.4%, front 68 -> 95 us. Reverted.)
// Bt written directly from phase-3 registers; per-head conv in phase 5.
// grid (512, 2), block 256.
// ---------------------------------------------------------------------------
__global__ __launch_bounds__(256) void k_front_fused(
    const float* __restrict__ x, const bf16* __restrict__ WiFb, const bf16* __restrict__ WiBb,
    const float* __restrict__ cwF, const float* __restrict__ cbF,
    const float* __restrict__ cwB, const float* __restrict__ cbB,
    const float* __restrict__ dtbF, const float* __restrict__ dtbB,
    const float* __restrict__ AlF, const float* __restrict__ AlB,
    const float* __restrict__ DpF, const float* __restrict__ DpB,
    bf16* __restrict__ Z, bf16* __restrict__ XBC2, float* __restrict__ DTV,
    bf16* __restrict__ Y, bf16* __restrict__ ST, float* __restrict__ CDb)
{
    const int tid  = threadIdx.x;
    const int wave = tid >> 6, lane = tid & 63;
    const int ln15 = lane & 15, q = lane >> 4;
    const int ch16 = 16 * wave + ln15;   // this thread's channel within a 64-ch tile
    const int dir  = blockIdx.y;
    const bf16* Wi = dir ? WiBb : WiFb;
    const int t0 = blockIdx.x * 64;
    const int batch = t0 >> 11, l0 = t0 & (L_ - 1);
    const int cc = l0 >> 6;   // chunk index
    const size_t rowbase = (size_t)dir * T_ + t0;
    const float* Al = dir ? AlB : AlF;
    const float* Dp = dir ? DpB : DpF;
    const float* cw = dir ? cwB : cwF;
    const float* cb = dir ? cbB : cbF;

    __shared__ __align__(16) short xs[80][136];    // tokens l0-16 .. l0+63
    __shared__ __align__(16) short Bs[64][72];     // B tile; later Ms / Yd stage
    __shared__ __align__(16) short Cs[64][72];     // C tile; later Xt
    __shared__ __align__(16) short Bt[64][72];     // B^T (written direct in phase 3)
    __shared__ float dts2[NH_][64];                // dt per (head, token)
    __shared__ float Acs4[NH_][64];
    __shared__ float decs4[NH_][64];

    // ---- phase 0: stage x ----
    for (int u = tid; u < 1280; u += 256) {
        int r = u >> 4, g = u & 15;
        int l = l0 - 16 + r;
        short8 v = {0, 0, 0, 0, 0, 0, 0, 0};
        if (l >= 0) {
            int sl = dir ? (L_ - 1 - l) : l;
            const float* px = x + ((size_t)batch * L_ + sl) * DM_ + g * 8;
            float4 v0 = *(const float4*)px;
            float4 v1 = *(const float4*)(px + 4);
            v = (short8){ f2bs(v0.x), f2bs(v0.y), f2bs(v0.z), f2bs(v0.w),
                          f2bs(v1.x), f2bs(v1.y), f2bs(v1.z), f2bs(v1.w) };
        }
        *(short8*)&xs[r][g * 8] = v;
    }
    __syncthreads();   // B0: xs ready

    // ---- phase 1: dt (wave w = 16-token strip w) -> dts2 + DTV ----
    {
        short8 bfr[4];
#pragma unroll
        for (int ks = 0; ks < 4; ++ks) {
            short8 v = {0, 0, 0, 0, 0, 0, 0, 0};
            if (ln15 < 4) v = *(const short8*)(Wi + (size_t)(640 + ln15) * DM_ + ks * 32 + q * 8);
            bfr[ks] = v;
        }
        const float* dtb = dir ? dtbB : dtbF;
        f32x4 acc = (f32x4){0.f, 0.f, 0.f, 0.f};
#pragma unroll
        for (int ks = 0; ks < 4; ++ks) {
            short8 afr = *(const short8*)&xs[16 + 16 * wave + ln15][ks * 32 + q * 8];
            acc = __builtin_amdgcn_mfma_f32_16x16x32_bf16(afr, bfr[ks], acc, 0, 0, 0);
        }
        if (ln15 < 4) {
            float bias = dtb[ln15];
#pragma unroll
            for (int rg = 0; rg < 4; ++rg) {
                int l = 16 * wave + 4 * q + rg;
                float dv = softplusf_(acc[rg] + bias);
                DTV[(rowbase + l) * NH_ + ln15] = dv;
                dts2[ln15][l] = dv;
            }
        }
    }

    // ---- phase 2: Z tiles (4), barrier-free ----
#pragma unroll
    for (int zt = 0; zt < 4; ++zt) {
        const int c0 = zt * 64;
        short8 wf[4];
#pragma unroll
        for (int ks = 0; ks < 4; ++ks)
            wf[ks] = *(const short8*)(Wi + (size_t)(c0 + ch16) * DM_ + ks * 32 + q * 8);
#pragma unroll
        for (int ct = 0; ct < 4; ++ct) {
            f32x4 acc = (f32x4){0.f, 0.f, 0.f, 0.f};
#pragma unroll
            for (int ks = 0; ks < 4; ++ks) {
                short8 xf = *(const short8*)&xs[16 + 16 * ct + ln15][ks * 32 + q * 8];
                acc = __builtin_amdgcn_mfma_f32_16x16x32_bf16(wf[ks], xf, acc, 0, 0, 0);
            }
            S4 s = { f2bs(acc[0]), f2bs(acc[1]), f2bs(acc[2]), f2bs(acc[3]) };
            *(S4*)(Z + (rowbase + 16 * ct + ln15) * DI_ + c0 + 16 * wave + 4 * q) = s;
        }
    }

    // ---- phase 3: B and C conv tiles, in-register taps, no barriers ----
    short8 bcur[4], bnxt[4];
#pragma unroll
    for (int ks = 0; ks < 4; ++ks)
        bcur[ks] = *(const short8*)(Wi + (size_t)(512 + ch16) * DM_ + ks * 32 + q * 8);

    for (int it = 0; it < 2; ++it) {   // it=0: B (Wi rows 512+), it=1: C (576+)
        f32x4 acc[5];
#pragma unroll
        for (int mt = 0; mt < 5; ++mt) acc[mt] = (f32x4){0.f, 0.f, 0.f, 0.f};
#pragma unroll
        for (int ks = 0; ks < 4; ++ks)
#pragma unroll
            for (int mt = 0; mt < 5; ++mt) {
                short8 afr = *(const short8*)&xs[16 * mt + ln15][ks * 32 + q * 8];
                acc[mt] = __builtin_amdgcn_mfma_f32_16x16x32_bf16(afr, bcur[ks], acc[mt], 0, 0, 0);
            }
        const int rnext = it ? 256 : 576;   // B -> C -> X0
#pragma unroll
        for (int ks = 0; ks < 4; ++ks)
            bnxt[ks] = *(const short8*)(Wi + (size_t)(rnext + ch16) * DM_ + ks * 32 + q * 8);
        const int gch = (it ? 320 : 256) + ch16;
        float wb = cb[gch], wv[4];
#pragma unroll
        for (int k = 0; k < 4; ++k) wv[k] = cw[gch * 4 + k];
#pragma unroll
        for (int mt = 1; mt <= 4; ++mt) {
            float p[3];
#pragma unroll
            for (int j = 0; j < 3; ++j) {
                float up = __shfl_up(acc[mt][j + 1], 16);
                float pw = __shfl(acc[mt - 1][j + 1], ln15 + 48);
                p[j] = (q == 0) ? pw : up;
            }
            float P[7] = { p[0], p[1], p[2], acc[mt][0], acc[mt][1], acc[mt][2], acc[mt][3] };
            short o[4];
#pragma unroll
            for (int rg = 0; rg < 4; ++rg) {
                float s = wb;
#pragma unroll
                for (int k = 0; k < 4; ++k) s += P[rg + k] * wv[k];
                s = s * sigmoidf_(s);
                o[rg] = f2bs(s);
                int row = 16 * (mt - 1) + 4 * q + rg;
                if (it == 0) Bs[row][ch16] = o[rg];
                else         Cs[row][ch16] = o[rg];
            }
            if (it == 0) {
                // channel-major B slice -> Bt direct (no phase-4 transpose)
                *(S4*)&Bt[ch16][16 * (mt - 1) + 4 * q] = (S4){ o[0], o[1], o[2], o[3] };
            }
        }
#pragma unroll
        for (int ks = 0; ks < 4; ++ks) bcur[ks] = bnxt[ks];
    }
    __syncthreads();   // B1: Bs, Cs, Bt, dts2 ready

    // ---- phase 4: scans, C global store, G = C B^T ----
    {
        const int h = wave, l = lane;
        const float Ah = -__expf(Al[h]);
        float dt = dts2[h][l];
        float s = dt * Ah;
#pragma unroll
        for (int off = 1; off < 64; off <<= 1) {
            float t2 = __shfl_up(s, off);
            if (l >= off) s += t2;
        }
        Acs4[h][l] = s;
        float alast = __shfl(s, 63);
        decs4[h][l] = expneg_(alast - s);
        if (l == 0) CDb[(((size_t)dir * B_ + batch) * NH_ + h) * NC_ + cc] = expneg_(alast);
    }
    // coalesced C -> XBC2 global (tail consumes it)
    for (int u = tid; u < 512; u += 256) {
        int r = u >> 3, g = u & 7;
        *(short8*)(XBC2 + (rowbase + r) * DBC_ + 64 + g * 8) = *(const short8*)&Cs[r][g * 8];
    }
    // G = C B^T once (head-independent); A-frag = own-wave Cs rows
    f32x4 a1[4];
#pragma unroll
    for (int ct = 0; ct < 4; ++ct) a1[ct] = (f32x4){0.f, 0.f, 0.f, 0.f};
#pragma unroll
    for (int ks = 0; ks < 2; ++ks) {
        short8 afr = *(const short8*)&Cs[16 * wave + ln15][ks * 32 + q * 8];
#pragma unroll
        for (int ct = 0; ct < 4; ++ct) {
            short8 bfr = *(const short8*)&Bs[16 * ct + ln15][ks * 32 + q * 8];
            a1[ct] = __builtin_amdgcn_mfma_f32_16x16x32_bf16(afr, bfr, a1[ct], 0, 0, 0);
        }
    }

    // ---- phase 5: per-head {conv-X in-reg -> Xt, mask, Yd, st} ----
    for (int h = 0; h < NH_; ++h) {
        const float Dh = Dp[h];
        // conv MFMA for head h's X channels (reads xs + bcur regs only)
        f32x4 acc[5];
#pragma unroll
        for (int mt = 0; mt < 5; ++mt) acc[mt] = (f32x4){0.f, 0.f, 0.f, 0.f};
#pragma unroll
        for (int ks = 0; ks < 4; ++ks)
#pragma unroll
            for (int mt = 0; mt < 5; ++mt) {
                short8 afr = *(const short8*)&xs[16 * mt + ln15][ks * 32 + q * 8];
                acc[mt] = __builtin_amdgcn_mfma_f32_16x16x32_bf16(afr, bcur[ks], acc[mt], 0, 0, 0);
            }
        if (h < NH_ - 1) {
#pragma unroll
            for (int ks = 0; ks < 4; ++ks)
                bnxt[ks] = *(const short8*)(Wi + (size_t)(320 + 64 * h + ch16) * DM_
                                            + ks * 32 + q * 8);
        }
        // taps + silu + dt fold -> 4 x S4 (token-major within lane = Xt row slice)
        const int gch = 64 * h + ch16;
        float wb = cb[gch], wv[4];
#pragma unroll
        for (int k = 0; k < 4; ++k) wv[k] = cw[gch * 4 + k];
        S4 xv[4];
#pragma unroll
        for (int mt = 1; mt <= 4; ++mt) {
            float p[3];
#pragma unroll
            for (int j = 0; j < 3; ++j) {
                float up = __shfl_up(acc[mt][j + 1], 16);
                float pw = __shfl(acc[mt - 1][j + 1], ln15 + 48);
                p[j] = (q == 0) ? pw : up;
            }
            float P[7] = { p[0], p[1], p[2], acc[mt][0], acc[mt][1], acc[mt][2], acc[mt][3] };
            short o[4];
#pragma unroll
            for (int rg = 0; rg < 4; ++rg) {
                float s = wb;
#pragma unroll
                for (int k = 0; k < 4; ++k) s += P[rg + k] * wv[k];
                s = s * sigmoidf_(s);
                o[rg] = f2bs(s * dts2[h][16 * (mt - 1) + 4 * q + rg]);
            }
            xv[mt - 1] = (S4){ o[0], o[1], o[2], o[3] };
        }
        __syncthreads();   // A_h: prior Xt readers done (h=0: Cs/Bs phase-4 consumers done)

        // write Xt (=Cs): row ch16 (wave-private), cols = tokens, S4 each
#pragma unroll
        for (int mt = 0; mt < 4; ++mt)
            *(S4*)&Cs[ch16][16 * mt + 4 * q] = xv[mt];
        // mask+decay from hoisted a1 -> Ms (=Bs, own-wave rows)
#pragma unroll
        for (int ct = 0; ct < 4; ++ct)
#pragma unroll
            for (int rg = 0; rg < 4; ++rg) {
                int l = 16 * wave + 4 * q + rg, s = 16 * ct + ln15;
                float m = (s <= l) ? a1[ct][rg] * expneg_(Acs4[h][l] - Acs4[h][s]) : 0.f;
                Bs[l][s] = f2bs(m);
            }
        __syncthreads();   // B_h: Xt ready

        // step 2: Yd = M @ Xdt
        f32x4 a2[4];
#pragma unroll
        for (int ct = 0; ct < 4; ++ct) a2[ct] = (f32x4){0.f, 0.f, 0.f, 0.f};
#pragma unroll
        for (int ks = 0; ks < 2; ++ks) {
            short8 afr = *(const short8*)&Bs[16 * wave + ln15][ks * 32 + q * 8];
#pragma unroll
            for (int ct = 0; ct < 4; ++ct) {
                short8 bfr = *(const short8*)&Cs[16 * ct + ln15][ks * 32 + q * 8];
                a2[ct] = __builtin_amdgcn_mfma_f32_16x16x32_bf16(afr, bfr, a2[ct], 0, 0, 0);
            }
        }
        // Yd tile into Bs (own rows), then coalesced 16 B/lane store
        float rdt[4];
#pragma unroll
        for (int rg = 0; rg < 4; ++rg) rdt[rg] = frcp_(dts2[h][16 * wave + 4 * q + rg]);
#pragma unroll
        for (int ct = 0; ct < 4; ++ct)
#pragma unroll
            for (int rg = 0; rg < 4; ++rg) {
                int l = 16 * wave + 4 * q + rg, p = 16 * ct + ln15;
                float xraw = bs2f(Cs[p][l]) * rdt[rg];
                Bs[l][p] = f2bs(a2[ct][rg] + Dh * xraw);
            }
#pragma unroll
        for (int i = 0; i < 2; ++i) {
            int row = 16 * wave + (lane >> 3) + 8 * i;
            int g = (lane & 7) * 8;
            short8 v = *(const short8*)&Bs[row][g];
            *(short8*)(Y + (rowbase + row) * DI_ + h * HD_ + g) = v;
        }
        // step 3: st[p][n] = sum_l (Xdt^T * dec)[p][l] * B^T[n][l]
        f32x4 a3[4];
#pragma unroll
        for (int ct = 0; ct < 4; ++ct) a3[ct] = (f32x4){0.f, 0.f, 0.f, 0.f};
#pragma unroll
        for (int ks = 0; ks < 2; ++ks) {
            short8 af = *(const short8*)&Cs[16 * wave + ln15][ks * 32 + q * 8];
            short8 afs;
#pragma unroll
            for (int j = 0; j < 8; ++j) {
                int l2 = ks * 32 + q * 8 + j;
                afs[j] = f2bs(bs2f(af[j]) * decs4[h][l2]);
            }
#pragma unroll
            for (int ct = 0; ct < 4; ++ct) {
                short8 bfr = *(const short8*)&Bt[16 * ct + ln15][ks * 32 + q * 8];
                a3[ct] = __builtin_amdgcn_mfma_f32_16x16x32_bf16(afs, bfr, a3[ct], 0, 0, 0);
            }
        }
        size_t sb = ((((size_t)dir * B_ + batch) * NC_ + cc) * NH_ + h) * 4096;
#pragma unroll
        for (int ct = 0; ct < 4; ++ct)
#pragma unroll
            for (int rg = 0; rg < 4; ++rg) {
                int p = 16 * wave + 4 * q + rg, n = 16 * ct + ln15;
                ST[sb + p * 64 + n] = f2b(a3[ct][rg]);
            }
#pragma unroll
        for (int ks = 0; ks < 4; ++ks) bcur[ks] = bnxt[ks];
    }
}

// ---------------------------------------------------------------------------
// K3 v3: inter-chunk scan, in place, 4 elem/thread (S4).
// (unchanged — cdr preload + 8-deep prefetch, fully unrolled)
// grid (256, 2), block 256.
// ---------------------------------------------------------------------------
__global__ __launch_bounds__(256) void k_scan(bf16* __restrict__ ST, const float* __restrict__ CDb)
{
    const int tid = threadIdx.x;
    const int dir = blockIdx.y;
    const int bx = blockIdx.x;                 // b*16 + h*4 + sg
    const int b = bx >> 4, h = (bx >> 2) & 3, sg = bx & 3;
    const size_t cdbase = (((size_t)dir * B_ + b) * NH_ + h) * NC_;
    const size_t base0 = (((size_t)dir * B_ + b) * NC_ * NH_ + h) * 4096
                       + (size_t)(sg * 256 + tid) * 4;
    const size_t cstride = (size_t)NH_ * 4096;   // chunk stride in elements

    // decay factors fully preloaded -> off the serial carry chain
    float cdr[32];
#pragma unroll
    for (int i = 0; i < 8; ++i) {
        float4 v = *(const float4*)(CDb + cdbase + i * 4);
        cdr[i * 4 + 0] = v.x; cdr[i * 4 + 1] = v.y;
        cdr[i * 4 + 2] = v.z; cdr[i * 4 + 3] = v.w;
    }
    // 8-deep ST prefetch
    S4 buf[8];
#pragma unroll
    for (int i = 0; i < 8; ++i)
        buf[i] = *(const S4*)(ST + base0 + (size_t)i * cstride);

    float carry[4] = {0.f, 0.f, 0.f, 0.f};
#pragma unroll
    for (int c = 0; c < NC_; ++c) {
        S4 cur = buf[c & 7];
        if (c + 8 < NC_)
            buf[c & 7] = *(const S4*)(ST + base0 + (size_t)(c + 8) * cstride);
        S4 st4 = { f2bs(carry[0]), f2bs(carry[1]), f2bs(carry[2]), f2bs(carry[3]) };
        *(S4*)(ST + base0 + (size_t)c * cstride) = st4;
        float cd = cdr[c];
        carry[0] = carry[0] * cd + bs2f(cur.a);
        carry[1] = carry[1] * cd + bs2f(cur.b);
        carry[2] = carry[2] * cd + bs2f(cur.c);
        carry[3] = carry[3] * cd + bs2f(cur.d);
    }
}

// ---------------------------------------------------------------------------
// K4 v5 (MFMA, FUSED offdiag + gate/RMSNorm + out-projection, 8 waves):
// (unchanged — issue-early ST prefetch + LDS-staged Ps2, C in regs)
// grid: (32, 16), block 512.
// ---------------------------------------------------------------------------
__global__ __launch_bounds__(512) void k_tail_fused(
    const bf16* __restrict__ XBC2, const float* __restrict__ DTV,
    const float* __restrict__ AlF, const float* __restrict__ AlB,
    const bf16* __restrict__ ST, const bf16* __restrict__ Z,
    const float* __restrict__ nwF, const float* __restrict__ nwB,
    const bf16* __restrict__ Y,
    const bf16* __restrict__ WoFb, const bf16* __restrict__ WoBb,
    float* __restrict__ out)
{
    const int tid = threadIdx.x;
    const int wave = tid >> 6, lane = tid & 63;
    const int ln15 = lane & 15, q = lane >> 4;
    const int grp = wave >> 2, strip = wave & 3;   // grp: head-pair member / N-half
    const int c = blockIdx.x, b = blockIdx.y;
    const int pt0 = b * L_ + c * 64;               // physical token base

    __shared__ __align__(16) short Ps2[2][64][72];
    __shared__ __align__(16) short Yz[64][264];
    __shared__ float eA[NH_][64];

    f32x4 acc[4];
#pragma unroll
    for (int ct = 0; ct < 4; ++ct) acc[ct] = (f32x4){0.f, 0.f, 0.f, 0.f};

    for (int d = 0; d < 2; ++d) {
        const int cd = d ? (NC_ - 1 - c) : c;
        const size_t rowbase = (size_t)d * T_ + (size_t)b * L_ + cd * 64;
        const float* Al = d ? AlB : AlF;
        const float* nw = d ? nwB : nwF;
        const bf16* Wo = d ? WoBb : WoFb;

        if (d) __syncthreads();   // dir0's Yz/Ps2 reads fully done before restage

        // ---- T14 issue-early: all 4 heads' ST fragments (4 short8/thread) ----
        short8 stq[4];
        const size_t sbase = ((((size_t)d * B_ + b) * NC_ + cd) * NH_) * 4096;
#pragma unroll
        for (int i = 0; i < 4; ++i) {
            int u = tid + 512 * i;
            int hh = u >> 9, r = (u >> 3) & 63, g = u & 7;
            stq[i] = *(const short8*)(ST + sbase + (size_t)hh * 4096 + r * 64 + g * 8);
        }

        // decay prefixes: waves 0-3, head = wave
        if (wave < NH_) {
            float A = -__expf(Al[wave]);
            float s = DTV[(rowbase + lane) * NH_ + wave] * A;
#pragma unroll
            for (int off = 1; off < 64; off <<= 1) {
                float t2 = __shfl_up(s, off);
                if (lane >= off) s += t2;
            }
            eA[wave][lane] = expneg_(s);
        }
        // stage Yd: 2048 short8, 4 per thread
#pragma unroll
        for (int i = 0; i < 4; ++i) {
            int u = tid + 512 * i;
            int r = u >> 5, g = u & 31;
            *(short8*)&Yz[r][g * 8] = *(const short8*)(Y + (rowbase + r) * DI_ + g * 8);
        }
        // C fragment in regs (A-operand), reused for both heads of this wave
        short8 afr[2];
#pragma unroll
        for (int ks = 0; ks < 2; ++ks)
            afr[ks] = *(const short8*)(XBC2 + (rowbase + 16 * strip + ln15) * DBC_
                                       + 64 + ks * 32 + q * 8);
        // write pr=0 Ps2 (heads 0,1) from prefetched regs — covered by B1
#pragma unroll
        for (int i = 0; i < 2; ++i) {
            int u = tid + 512 * i;
            int hh = u >> 9, r = (u >> 3) & 63, g = u & 7;
            *(short8*)&Ps2[hh][r][g * 8] = stq[i];
        }
        __syncthreads();   // B1: Yz, eA, Ps2(h0,h1) ready

        // head pairs: group 0-3 -> head 2*pr, group 4-7 -> head 2*pr+1
        for (int pr = 0; pr < 2; ++pr) {
            const int h = 2 * pr + grp;
            f32x4 a2[4];
#pragma unroll
            for (int ct = 0; ct < 4; ++ct) a2[ct] = (f32x4){0.f, 0.f, 0.f, 0.f};
#pragma unroll
            for (int ks = 0; ks < 2; ++ks)
#pragma unroll
                for (int ct = 0; ct < 4; ++ct) {
                    short8 bfr = *(const short8*)&Ps2[grp][16 * ct + ln15][ks * 32 + q * 8];
                    a2[ct] = __builtin_amdgcn_mfma_f32_16x16x32_bf16(afr[ks], bfr, a2[ct], 0, 0, 0);
                }
#pragma unroll
            for (int ct = 0; ct < 4; ++ct)
#pragma unroll
                for (int rg = 0; rg < 4; ++rg) {
                    int l = 16 * strip + 4 * q + rg, p = 16 * ct + ln15;
                    float yv = bs2f(Yz[l][h * 64 + p]) + a2[ct][rg] * eA[h][l];
                    Yz[l][h * 64 + p] = f2bs(yv);   // disjoint (l, h-cols) per wave
                }
            if (pr == 0) {
                __syncthreads();   // B2: pr0 Ps2 consumers done
                // write pr=1 Ps2 (heads 2,3) from prefetched regs
#pragma unroll
                for (int i = 0; i < 2; ++i) {
                    int u = tid + 512 * (i + 2);
                    int hh = (u >> 9) - 2, r = (u >> 3) & 63, g = u & 7;
                    *(short8*)&Ps2[hh][r][g * 8] = stq[i + 2];
                }
                __syncthreads();   // B3: pr1 Ps2 ready
            }
        }
        __syncthreads();   // B4: all Yz head-updates visible

        // gate + RMSNorm: wave rows 8*wave .. 8*wave+7 (wave-private)
        float nwv[4];
#pragma unroll
        for (int j = 0; j < 4; ++j) nwv[j] = nw[lane * 4 + j];
#pragma unroll
        for (int rr = 0; rr < 8; ++rr) {
            int row = 8 * wave + rr;
            S4 zv4 = *(const S4*)(Z + (rowbase + row) * DI_ + lane * 4);
            short zr[4] = { zv4.a, zv4.b, zv4.c, zv4.d };
            float v[4]; float ss = 0.f;
#pragma unroll
            for (int j = 0; j < 4; ++j) {
                float yv = bs2f(Yz[row][lane * 4 + j]);
                float zf = bs2f(zr[j]);
                v[j] = yv * zf * sigmoidf_(zf);
                ss += v[j] * v[j];
            }
#pragma unroll
            for (int off = 1; off < 64; off <<= 1) ss += __shfl_xor(ss, off);
            float rn = rsqrtf(ss * (1.f / 256.f) + 1e-5f);
#pragma unroll
            for (int j = 0; j < 4; ++j)
                Yz[row][lane * 4 + j] = f2bs(v[j] * rn * nwv[j]);
        }
        __syncthreads();   // B5: final Yz visible to all waves

        // out-projection accumulate; wave = (strip, Nhalf=grp); dir1 row-reversed
        const int prow = 16 * strip + ln15;
        const int lr = d ? 63 - prow : prow;
        short8 wf[4], wfn[4];
#pragma unroll
        for (int ct = 0; ct < 4; ++ct)
            wf[ct] = *(const short8*)(Wo + (size_t)(16 * (4 * grp + ct) + ln15) * DI_ + q * 8);
#pragma unroll
        for (int it = 0; it < 8; ++it) {
            const int k0 = (it >> 1) * 64 + (it & 1) * 32;
            if (it < 7) {
                const int k0n = ((it + 1) >> 1) * 64 + ((it + 1) & 1) * 32;
#pragma unroll
                for (int ct = 0; ct < 4; ++ct)
                    wfn[ct] = *(const short8*)(Wo + (size_t)(16 * (4 * grp + ct) + ln15) * DI_
                                               + k0n + q * 8);
            }
            short8 afr2 = *(const short8*)&Yz[lr][k0 + q * 8];
#pragma unroll
            for (int ct = 0; ct < 4; ++ct)
                acc[ct] = __builtin_amdgcn_mfma_f32_16x16x32_bf16(afr2, wf[ct], acc[ct], 0, 0, 0);
#pragma unroll
            for (int ct = 0; ct < 4; ++ct) wf[ct] = wfn[ct];
        }
    }

    // write out (f32), both dirs accumulated
#pragma unroll
    for (int ct = 0; ct < 4; ++ct)
#pragma unroll
        for (int rg = 0; rg < 4; ++rg) {
            int row = 16 * strip + 4 * q + rg, col = 16 * (4 * grp + ct) + ln15;
            out[((size_t)(pt0 + row)) * DM_ + col] = acc[ct][rg];
        }
}

// ---------------------------------------------------------------------------
extern "C" void kernel_launch(void* const* d_in, const int* in_sizes, int n_in,
                              void* d_out, int out_size, void* d_ws, size_t ws_size,
                              hipStream_t stream)
{
    const float* x    = (const float*)d_in[0];
    const float* WiF  = (const float*)d_in[1];
    const float* cwF  = (const float*)d_in[2];
    const float* cbF  = (const float*)d_in[3];
    const float* dtbF = (const float*)d_in[4];
    const float* AlF  = (const float*)d_in[5];
    const float* DpF  = (const float*)d_in[6];
    const float* nwF  = (const float*)d_in[7];
    const float* WoF  = (const float*)d_in[8];
    const float* WiB  = (const float*)d_in[9];
    const float* cwB  = (const float*)d_in[10];
    const float* cbB  = (const float*)d_in[11];
    const float* dtbB = (const float*)d_in[12];
    const float* AlB  = (const float*)d_in[13];
    const float* DpB  = (const float*)d_in[14];
    const float* nwB  = (const float*)d_in[15];
    const float* WoB  = (const float*)d_in[16];

    const size_t nZ    = (size_t)2 * T_ * DI_;       // bf16
    const size_t nXBC2 = (size_t)2 * T_ * DBC_;      // bf16 (C only, stride 128)
    const size_t nY    = (size_t)2 * T_ * DI_;       // bf16 (Yd)
    const size_t nST   = (size_t)2 * B_ * NC_ * NH_ * HD_ * DS_;  // bf16
    const size_t nWb   = (size_t)2 * NWI + 2 * NWO;  // bf16 weight copies
    const size_t nDTV  = (size_t)2 * T_ * NH_;       // f32
    const size_t nCD   = (size_t)2 * B_ * NH_ * NC_; // f32
    const size_t need = (nZ + nXBC2 + nY + nST + nWb) * sizeof(bf16)
                      + (nDTV + nCD) * sizeof(float);
    if (ws_size < need) return;

    char* p = (char*)d_ws;
    bf16* Z    = (bf16*)p;            p += nZ * sizeof(bf16);
    bf16* XBC2 = (bf16*)p;            p += nXBC2 * sizeof(bf16);
    bf16* Yb   = (bf16*)p;            p += nY * sizeof(bf16);
    bf16* ST   = (bf16*)p;            p += nST * sizeof(bf16);
    bf16* WiFb = (bf16*)p;            p += (size_t)NWI * sizeof(bf16);
    bf16* WiBb = (bf16*)p;            p += (size_t)NWI * sizeof(bf16);
    bf16* WoFb = (bf16*)p;            p += (size_t)NWO * sizeof(bf16);
    bf16* WoBb = (bf16*)p;            p += (size_t)NWO * sizeof(bf16);
    float* DTV = (float*)p;           p += nDTV * sizeof(float);
    float* CDb = (float*)p;

    k_prep<<<128, 256, 0, stream>>>(WiF, WiB, WoF, WoB, WiFb, WiBb, WoFb, WoBb);
    k_front_fused<<<dim3(512, 2), 256, 0, stream>>>(x, WiFb, WiBb, cwF, cbF, cwB, cbB,
                                                    dtbF, dtbB, AlF, AlB, DpF, DpB,
                                                    Z, XBC2, DTV, Yb, ST, CDb);
    k_scan<<<dim3(256, 2), 256, 0, stream>>>(ST, CDb);
    k_tail_fused<<<dim3(NC_, B_), 512, 0, stream>>>(XBC2, DTV, AlF, AlB, ST, Z,
                                                    nwF, nwB, Yb, WoFb, WoBb, (float*)d_out);
}

// Round 18
// 222.696 us; speedup vs baseline: 1.1300x; 1.0082x over previous
//
#include <hip/hip_runtime.h>
#include <hip/hip_bf16.h>
#include <cmath>

#define B_    16
#define L_    2048
#define T_    32768   // B_*L_
#define DM_   128
#define DI_   256
#define DBC_  128     // XBC2 row stride: C stored at cols 64..127 (B not materialized)
#define DS_   64
#define HD_   64
#define NH_   4
#define NC_   32      // chunks per sequence (L_/64)

typedef __hip_bfloat16 bf16;
typedef __attribute__((ext_vector_type(8))) short short8;
typedef __attribute__((ext_vector_type(4))) float f32x4;

__device__ __forceinline__ float b2f(bf16 v) { return __bfloat162float(v); }
__device__ __forceinline__ bf16  f2b(float f) { return __float2bfloat16(f); }
__device__ __forceinline__ short f2bs(float f) { bf16 h = __float2bfloat16(f); return *reinterpret_cast<short*>(&h); }
__device__ __forceinline__ float bs2f(short s) { bf16 h = *reinterpret_cast<bf16*>(&s); return __bfloat162float(h); }
// fast transcendentals: v_exp_f32 / v_log_f32 / v_rcp_f32 (1-2 ulp, fine for bf16)
__device__ __forceinline__ float frcp_(float x) { return __builtin_amdgcn_rcpf(x); }
__device__ __forceinline__ float sigmoidf_(float x) { return frcp_(1.f + __expf(-x)); }
__device__ __forceinline__ float softplusf_(float x) { return (x > 20.f) ? x : __logf(1.f + __expf(x)); }
__device__ __forceinline__ float expneg_(float x) { return __expf(fminf(x, 0.f)); }

struct __align__(8) S4 { short a, b, c, d; };

#define NWI 82432   // 644*128
#define NWO 32768   // 128*256

// ---------------------------------------------------------------------------
// K0: one-time f32 -> bf16 conversion of Wi_f/b, Wo_f/b (weights only).
// ---------------------------------------------------------------------------
__global__ __launch_bounds__(256) void k_prep(
    const float* __restrict__ WiF, const float* __restrict__ WiB,
    const float* __restrict__ WoF, const float* __restrict__ WoB,
    bf16* __restrict__ WiFb, bf16* __restrict__ WiBb,
    bf16* __restrict__ WoFb, bf16* __restrict__ WoBb)
{
    const int gid = blockIdx.x * 256 + threadIdx.x;
    const int stride = gridDim.x * 256;
    for (int i = gid; i < NWI / 4; i += stride) {
        float4 v = ((const float4*)WiF)[i];
        S4 s = { f2bs(v.x), f2bs(v.y), f2bs(v.z), f2bs(v.w) };
        ((S4*)WiFb)[i] = s;
        v = ((const float4*)WiB)[i];
        S4 t = { f2bs(v.x), f2bs(v.y), f2bs(v.z), f2bs(v.w) };
        ((S4*)WiBb)[i] = t;
    }
    for (int i = gid; i < NWO / 4; i += stride) {
        float4 v = ((const float4*)WoF)[i];
        S4 s = { f2bs(v.x), f2bs(v.y), f2bs(v.z), f2bs(v.w) };
        ((S4*)WoFb)[i] = s;
        v = ((const float4*)WoB)[i];
        S4 t = { f2bs(v.x), f2bs(v.y), f2bs(v.z), f2bs(v.w) };
        ((S4*)WoBb)[i] = t;
    }
}

// ---------------------------------------------------------------------------
// K1 v3 (MFMA, FUSED in_proj + conv + silu + intra-chunk SSM):
// (unchanged — R13/R16 best build, VGPR 68)
// grid (512, 2), block 256.
// ---------------------------------------------------------------------------
__global__ __launch_bounds__(256) void k_front_fused(
    const float* __restrict__ x, const bf16* __restrict__ WiFb, const bf16* __restrict__ WiBb,
    const float* __restrict__ cwF, const float* __restrict__ cbF,
    const float* __restrict__ cwB, const float* __restrict__ cbB,
    const float* __restrict__ dtbF, const float* __restrict__ dtbB,
    const float* __restrict__ AlF, const float* __restrict__ AlB,
    const float* __restrict__ DpF, const float* __restrict__ DpB,
    bf16* __restrict__ Z, bf16* __restrict__ XBC2, float* __restrict__ DTV,
    bf16* __restrict__ Y, bf16* __restrict__ ST, float* __restrict__ CDb)
{
    const int tid  = threadIdx.x;
    const int wave = tid >> 6, lane = tid & 63;
    const int ln15 = lane & 15, q = lane >> 4;
    const int ch16 = 16 * wave + ln15;   // this thread's channel within a 64-ch tile
    const int dir  = blockIdx.y;
    const bf16* Wi = dir ? WiBb : WiFb;
    const int t0 = blockIdx.x * 64;
    const int batch = t0 >> 11, l0 = t0 & (L_ - 1);
    const int cc = l0 >> 6;   // chunk index
    const size_t rowbase = (size_t)dir * T_ + t0;
    const float* Al = dir ? AlB : AlF;
    const float* Dp = dir ? DpB : DpF;
    const float* cw = dir ? cwB : cwF;
    const float* cb = dir ? cbB : cbF;

    __shared__ __align__(16) short xs[80][136];    // tokens l0-16 .. l0+63
    __shared__ __align__(16) short Bs[64][72];     // B tile; later Ms / Yd stage
    __shared__ __align__(16) short Cs[64][72];     // C tile; later Xt
    __shared__ __align__(16) short Bt[64][72];     // B^T (written direct in phase 3)
    __shared__ float dts2[NH_][64];                // dt per (head, token)
    __shared__ float Acs4[NH_][64];
    __shared__ float decs4[NH_][64];

    // ---- phase 0: stage x ----
    for (int u = tid; u < 1280; u += 256) {
        int r = u >> 4, g = u & 15;
        int l = l0 - 16 + r;
        short8 v = {0, 0, 0, 0, 0, 0, 0, 0};
        if (l >= 0) {
            int sl = dir ? (L_ - 1 - l) : l;
            const float* px = x + ((size_t)batch * L_ + sl) * DM_ + g * 8;
            float4 v0 = *(const float4*)px;
            float4 v1 = *(const float4*)(px + 4);
            v = (short8){ f2bs(v0.x), f2bs(v0.y), f2bs(v0.z), f2bs(v0.w),
                          f2bs(v1.x), f2bs(v1.y), f2bs(v1.z), f2bs(v1.w) };
        }
        *(short8*)&xs[r][g * 8] = v;
    }
    __syncthreads();   // B0: xs ready

    // ---- phase 1: dt (wave w = 16-token strip w) -> dts2 + DTV ----
    {
        short8 bfr[4];
#pragma unroll
        for (int ks = 0; ks < 4; ++ks) {
            short8 v = {0, 0, 0, 0, 0, 0, 0, 0};
            if (ln15 < 4) v = *(const short8*)(Wi + (size_t)(640 + ln15) * DM_ + ks * 32 + q * 8);
            bfr[ks] = v;
        }
        const float* dtb = dir ? dtbB : dtbF;
        f32x4 acc = (f32x4){0.f, 0.f, 0.f, 0.f};
#pragma unroll
        for (int ks = 0; ks < 4; ++ks) {
            short8 afr = *(const short8*)&xs[16 + 16 * wave + ln15][ks * 32 + q * 8];
            acc = __builtin_amdgcn_mfma_f32_16x16x32_bf16(afr, bfr[ks], acc, 0, 0, 0);
        }
        if (ln15 < 4) {
            float bias = dtb[ln15];
#pragma unroll
            for (int rg = 0; rg < 4; ++rg) {
                int l = 16 * wave + 4 * q + rg;
                float dv = softplusf_(acc[rg] + bias);
                DTV[(rowbase + l) * NH_ + ln15] = dv;
                dts2[ln15][l] = dv;
            }
        }
    }

    // ---- phase 2: Z tiles (4), barrier-free ----
#pragma unroll
    for (int zt = 0; zt < 4; ++zt) {
        const int c0 = zt * 64;
        short8 wf[4];
#pragma unroll
        for (int ks = 0; ks < 4; ++ks)
            wf[ks] = *(const short8*)(Wi + (size_t)(c0 + ch16) * DM_ + ks * 32 + q * 8);
#pragma unroll
        for (int ct = 0; ct < 4; ++ct) {
            f32x4 acc = (f32x4){0.f, 0.f, 0.f, 0.f};
#pragma unroll
            for (int ks = 0; ks < 4; ++ks) {
                short8 xf = *(const short8*)&xs[16 + 16 * ct + ln15][ks * 32 + q * 8];
                acc = __builtin_amdgcn_mfma_f32_16x16x32_bf16(wf[ks], xf, acc, 0, 0, 0);
            }
            S4 s = { f2bs(acc[0]), f2bs(acc[1]), f2bs(acc[2]), f2bs(acc[3]) };
            *(S4*)(Z + (rowbase + 16 * ct + ln15) * DI_ + c0 + 16 * wave + 4 * q) = s;
        }
    }

    // ---- phase 3: B and C conv tiles, in-register taps, no barriers ----
    short8 bcur[4], bnxt[4];
#pragma unroll
    for (int ks = 0; ks < 4; ++ks)
        bcur[ks] = *(const short8*)(Wi + (size_t)(512 + ch16) * DM_ + ks * 32 + q * 8);

    for (int it = 0; it < 2; ++it) {   // it=0: B (Wi rows 512+), it=1: C (576+)
        f32x4 acc[5];
#pragma unroll
        for (int mt = 0; mt < 5; ++mt) acc[mt] = (f32x4){0.f, 0.f, 0.f, 0.f};
#pragma unroll
        for (int ks = 0; ks < 4; ++ks)
#pragma unroll
            for (int mt = 0; mt < 5; ++mt) {
                short8 afr = *(const short8*)&xs[16 * mt + ln15][ks * 32 + q * 8];
                acc[mt] = __builtin_amdgcn_mfma_f32_16x16x32_bf16(afr, bcur[ks], acc[mt], 0, 0, 0);
            }
        const int rnext = it ? 256 : 576;   // B -> C -> X0
#pragma unroll
        for (int ks = 0; ks < 4; ++ks)
            bnxt[ks] = *(const short8*)(Wi + (size_t)(rnext + ch16) * DM_ + ks * 32 + q * 8);
        const int gch = (it ? 320 : 256) + ch16;
        float wb = cb[gch], wv[4];
#pragma unroll
        for (int k = 0; k < 4; ++k) wv[k] = cw[gch * 4 + k];
#pragma unroll
        for (int mt = 1; mt <= 4; ++mt) {
            float p[3];
#pragma unroll
            for (int j = 0; j < 3; ++j) {
                float up = __shfl_up(acc[mt][j + 1], 16);
                float pw = __shfl(acc[mt - 1][j + 1], ln15 + 48);
                p[j] = (q == 0) ? pw : up;
            }
            float P[7] = { p[0], p[1], p[2], acc[mt][0], acc[mt][1], acc[mt][2], acc[mt][3] };
            short o[4];
#pragma unroll
            for (int rg = 0; rg < 4; ++rg) {
                float s = wb;
#pragma unroll
                for (int k = 0; k < 4; ++k) s += P[rg + k] * wv[k];
                s = s * sigmoidf_(s);
                o[rg] = f2bs(s);
                int row = 16 * (mt - 1) + 4 * q + rg;
                if (it == 0) Bs[row][ch16] = o[rg];
                else         Cs[row][ch16] = o[rg];
            }
            if (it == 0) {
                // channel-major B slice -> Bt direct (no phase-4 transpose)
                *(S4*)&Bt[ch16][16 * (mt - 1) + 4 * q] = (S4){ o[0], o[1], o[2], o[3] };
            }
        }
#pragma unroll
        for (int ks = 0; ks < 4; ++ks) bcur[ks] = bnxt[ks];
    }
    __syncthreads();   // B1: Bs, Cs, Bt, dts2 ready

    // ---- phase 4: scans, C global store, G = C B^T ----
    {
        const int h = wave, l = lane;
        const float Ah = -__expf(Al[h]);
        float dt = dts2[h][l];
        float s = dt * Ah;
#pragma unroll
        for (int off = 1; off < 64; off <<= 1) {
            float t2 = __shfl_up(s, off);
            if (l >= off) s += t2;
        }
        Acs4[h][l] = s;
        float alast = __shfl(s, 63);
        decs4[h][l] = expneg_(alast - s);
        if (l == 0) CDb[(((size_t)dir * B_ + batch) * NH_ + h) * NC_ + cc] = expneg_(alast);
    }
    // coalesced C -> XBC2 global (tail consumes it)
    for (int u = tid; u < 512; u += 256) {
        int r = u >> 3, g = u & 7;
        *(short8*)(XBC2 + (rowbase + r) * DBC_ + 64 + g * 8) = *(const short8*)&Cs[r][g * 8];
    }
    // G = C B^T once (head-independent); A-frag = own-wave Cs rows
    f32x4 a1[4];
#pragma unroll
    for (int ct = 0; ct < 4; ++ct) a1[ct] = (f32x4){0.f, 0.f, 0.f, 0.f};
#pragma unroll
    for (int ks = 0; ks < 2; ++ks) {
        short8 afr = *(const short8*)&Cs[16 * wave + ln15][ks * 32 + q * 8];
#pragma unroll
        for (int ct = 0; ct < 4; ++ct) {
            short8 bfr = *(const short8*)&Bs[16 * ct + ln15][ks * 32 + q * 8];
            a1[ct] = __builtin_amdgcn_mfma_f32_16x16x32_bf16(afr, bfr, a1[ct], 0, 0, 0);
        }
    }

    // ---- phase 5: per-head {conv-X in-reg -> Xt, mask, Yd, st} ----
    for (int h = 0; h < NH_; ++h) {
        const float Dh = Dp[h];
        // conv MFMA for head h's X channels (reads xs + bcur regs only)
        f32x4 acc[5];
#pragma unroll
        for (int mt = 0; mt < 5; ++mt) acc[mt] = (f32x4){0.f, 0.f, 0.f, 0.f};
#pragma unroll
        for (int ks = 0; ks < 4; ++ks)
#pragma unroll
            for (int mt = 0; mt < 5; ++mt) {
                short8 afr = *(const short8*)&xs[16 * mt + ln15][ks * 32 + q * 8];
                acc[mt] = __builtin_amdgcn_mfma_f32_16x16x32_bf16(afr, bcur[ks], acc[mt], 0, 0, 0);
            }
        if (h < NH_ - 1) {
#pragma unroll
            for (int ks = 0; ks < 4; ++ks)
                bnxt[ks] = *(const short8*)(Wi + (size_t)(320 + 64 * h + ch16) * DM_
                                            + ks * 32 + q * 8);
        }
        // taps + silu + dt fold -> 4 x S4 (token-major within lane = Xt row slice)
        const int gch = 64 * h + ch16;
        float wb = cb[gch], wv[4];
#pragma unroll
        for (int k = 0; k < 4; ++k) wv[k] = cw[gch * 4 + k];
        S4 xv[4];
#pragma unroll
        for (int mt = 1; mt <= 4; ++mt) {
            float p[3];
#pragma unroll
            for (int j = 0; j < 3; ++j) {
                float up = __shfl_up(acc[mt][j + 1], 16);
                float pw = __shfl(acc[mt - 1][j + 1], ln15 + 48);
                p[j] = (q == 0) ? pw : up;
            }
            float P[7] = { p[0], p[1], p[2], acc[mt][0], acc[mt][1], acc[mt][2], acc[mt][3] };
            short o[4];
#pragma unroll
            for (int rg = 0; rg < 4; ++rg) {
                float s = wb;
#pragma unroll
                for (int k = 0; k < 4; ++k) s += P[rg + k] * wv[k];
                s = s * sigmoidf_(s);
                o[rg] = f2bs(s * dts2[h][16 * (mt - 1) + 4 * q + rg]);
            }
            xv[mt - 1] = (S4){ o[0], o[1], o[2], o[3] };
        }
        __syncthreads();   // A_h: prior Xt readers done (h=0: Cs/Bs phase-4 consumers done)

        // write Xt (=Cs): row ch16 (wave-private), cols = tokens, S4 each
#pragma unroll
        for (int mt = 0; mt < 4; ++mt)
            *(S4*)&Cs[ch16][16 * mt + 4 * q] = xv[mt];
        // mask+decay from hoisted a1 -> Ms (=Bs, own-wave rows)
#pragma unroll
        for (int ct = 0; ct < 4; ++ct)
#pragma unroll
            for (int rg = 0; rg < 4; ++rg) {
                int l = 16 * wave + 4 * q + rg, s = 16 * ct + ln15;
                float m = (s <= l) ? a1[ct][rg] * expneg_(Acs4[h][l] - Acs4[h][s]) : 0.f;
                Bs[l][s] = f2bs(m);
            }
        __syncthreads();   // B_h: Xt ready

        // step 2: Yd = M @ Xdt
        f32x4 a2[4];
#pragma unroll
        for (int ct = 0; ct < 4; ++ct) a2[ct] = (f32x4){0.f, 0.f, 0.f, 0.f};
#pragma unroll
        for (int ks = 0; ks < 2; ++ks) {
            short8 afr = *(const short8*)&Bs[16 * wave + ln15][ks * 32 + q * 8];
#pragma unroll
            for (int ct = 0; ct < 4; ++ct) {
                short8 bfr = *(const short8*)&Cs[16 * ct + ln15][ks * 32 + q * 8];
                a2[ct] = __builtin_amdgcn_mfma_f32_16x16x32_bf16(afr, bfr, a2[ct], 0, 0, 0);
            }
        }
        // Yd tile into Bs (own rows), then coalesced 16 B/lane store
        float rdt[4];
#pragma unroll
        for (int rg = 0; rg < 4; ++rg) rdt[rg] = frcp_(dts2[h][16 * wave + 4 * q + rg]);
#pragma unroll
        for (int ct = 0; ct < 4; ++ct)
#pragma unroll
            for (int rg = 0; rg < 4; ++rg) {
                int l = 16 * wave + 4 * q + rg, p = 16 * ct + ln15;
                float xraw = bs2f(Cs[p][l]) * rdt[rg];
                Bs[l][p] = f2bs(a2[ct][rg] + Dh * xraw);
            }
#pragma unroll
        for (int i = 0; i < 2; ++i) {
            int row = 16 * wave + (lane >> 3) + 8 * i;
            int g = (lane & 7) * 8;
            short8 v = *(const short8*)&Bs[row][g];
            *(short8*)(Y + (rowbase + row) * DI_ + h * HD_ + g) = v;
        }
        // step 3: st[p][n] = sum_l (Xdt^T * dec)[p][l] * B^T[n][l]
        f32x4 a3[4];
#pragma unroll
        for (int ct = 0; ct < 4; ++ct) a3[ct] = (f32x4){0.f, 0.f, 0.f, 0.f};
#pragma unroll
        for (int ks = 0; ks < 2; ++ks) {
            short8 af = *(const short8*)&Cs[16 * wave + ln15][ks * 32 + q * 8];
            short8 afs;
#pragma unroll
            for (int j = 0; j < 8; ++j) {
                int l2 = ks * 32 + q * 8 + j;
                afs[j] = f2bs(bs2f(af[j]) * decs4[h][l2]);
            }
#pragma unroll
            for (int ct = 0; ct < 4; ++ct) {
                short8 bfr = *(const short8*)&Bt[16 * ct + ln15][ks * 32 + q * 8];
                a3[ct] = __builtin_amdgcn_mfma_f32_16x16x32_bf16(afs, bfr, a3[ct], 0, 0, 0);
            }
        }
        size_t sb = ((((size_t)dir * B_ + batch) * NC_ + cc) * NH_ + h) * 4096;
#pragma unroll
        for (int ct = 0; ct < 4; ++ct)
#pragma unroll
            for (int rg = 0; rg < 4; ++rg) {
                int p = 16 * wave + 4 * q + rg, n = 16 * ct + ln15;
                ST[sb + p * 64 + n] = f2b(a3[ct][rg]);
            }
#pragma unroll
        for (int ks = 0; ks < 4; ++ks) bcur[ks] = bnxt[ks];
    }
}

// ---------------------------------------------------------------------------
// K3 v3: inter-chunk scan, in place, 4 elem/thread (S4).
// (unchanged — cdr preload + 8-deep prefetch, fully unrolled)
// grid (256, 2), block 256.
// ---------------------------------------------------------------------------
__global__ __launch_bounds__(256) void k_scan(bf16* __restrict__ ST, const float* __restrict__ CDb)
{
    const int tid = threadIdx.x;
    const int dir = blockIdx.y;
    const int bx = blockIdx.x;                 // b*16 + h*4 + sg
    const int b = bx >> 4, h = (bx >> 2) & 3, sg = bx & 3;
    const size_t cdbase = (((size_t)dir * B_ + b) * NH_ + h) * NC_;
    const size_t base0 = (((size_t)dir * B_ + b) * NC_ * NH_ + h) * 4096
                       + (size_t)(sg * 256 + tid) * 4;
    const size_t cstride = (size_t)NH_ * 4096;   // chunk stride in elements

    // decay factors fully preloaded -> off the serial carry chain
    float cdr[32];
#pragma unroll
    for (int i = 0; i < 8; ++i) {
        float4 v = *(const float4*)(CDb + cdbase + i * 4);
        cdr[i * 4 + 0] = v.x; cdr[i * 4 + 1] = v.y;
        cdr[i * 4 + 2] = v.z; cdr[i * 4 + 3] = v.w;
    }
    // 8-deep ST prefetch
    S4 buf[8];
#pragma unroll
    for (int i = 0; i < 8; ++i)
        buf[i] = *(const S4*)(ST + base0 + (size_t)i * cstride);

    float carry[4] = {0.f, 0.f, 0.f, 0.f};
#pragma unroll
    for (int c = 0; c < NC_; ++c) {
        S4 cur = buf[c & 7];
        if (c + 8 < NC_)
            buf[c & 7] = *(const S4*)(ST + base0 + (size_t)(c + 8) * cstride);
        S4 st4 = { f2bs(carry[0]), f2bs(carry[1]), f2bs(carry[2]), f2bs(carry[3]) };
        *(S4*)(ST + base0 + (size_t)c * cstride) = st4;
        float cd = cdr[c];
        carry[0] = carry[0] * cd + bs2f(cur.a);
        carry[1] = carry[1] * cd + bs2f(cur.b);
        carry[2] = carry[2] * cd + bs2f(cur.c);
        carry[3] = carry[3] * cd + bs2f(cur.d);
    }
}

// ---------------------------------------------------------------------------
// K4 v6 (MFMA, offdiag + gate/RMSNorm + out-projection, DIR-SPLIT):
// The two directions move from a serial in-block loop to blockIdx.z —
// 1024 blocks (~24 waves/CU vs 16), per-block barrier chain halves
// (5 barriers). dir0 writes f32 `out`, dir1 writes f32 `Obuf` at the same
// physical coordinates (existing lr-mirroring maps dir1's logical rows);
// k_addout merges. Inner code identical to v5's per-dir body.
// grid: (32, 16, 2), block 512.
// ---------------------------------------------------------------------------
__global__ __launch_bounds__(512) void k_tail_fused(
    const bf16* __restrict__ XBC2, const float* __restrict__ DTV,
    const float* __restrict__ AlF, const float* __restrict__ AlB,
    const bf16* __restrict__ ST, const bf16* __restrict__ Z,
    const float* __restrict__ nwF, const float* __restrict__ nwB,
    const bf16* __restrict__ Y,
    const bf16* __restrict__ WoFb, const bf16* __restrict__ WoBb,
    float* __restrict__ out, float* __restrict__ Obuf)
{
    const int tid = threadIdx.x;
    const int wave = tid >> 6, lane = tid & 63;
    const int ln15 = lane & 15, q = lane >> 4;
    const int grp = wave >> 2, strip = wave & 3;   // grp: head-pair member / N-half
    const int c = blockIdx.x, b = blockIdx.y;
    const int d = blockIdx.z;
    const int pt0 = b * L_ + c * 64;               // physical token base

    __shared__ __align__(16) short Ps2[2][64][72];
    __shared__ __align__(16) short Yz[64][264];
    __shared__ float eA[NH_][64];

    f32x4 acc[4];
#pragma unroll
    for (int ct = 0; ct < 4; ++ct) acc[ct] = (f32x4){0.f, 0.f, 0.f, 0.f};

    const int cd = d ? (NC_ - 1 - c) : c;
    const size_t rowbase = (size_t)d * T_ + (size_t)b * L_ + cd * 64;
    const float* Al = d ? AlB : AlF;
    const float* nw = d ? nwB : nwF;
    const bf16* Wo = d ? WoBb : WoFb;
    float* outp = d ? Obuf : out;

    // ---- T14 issue-early: all 4 heads' ST fragments (4 short8/thread) ----
    short8 stq[4];
    const size_t sbase = ((((size_t)d * B_ + b) * NC_ + cd) * NH_) * 4096;
#pragma unroll
    for (int i = 0; i < 4; ++i) {
        int u = tid + 512 * i;
        int hh = u >> 9, r = (u >> 3) & 63, g = u & 7;
        stq[i] = *(const short8*)(ST + sbase + (size_t)hh * 4096 + r * 64 + g * 8);
    }

    // decay prefixes: waves 0-3, head = wave
    if (wave < NH_) {
        float A = -__expf(Al[wave]);
        float s = DTV[(rowbase + lane) * NH_ + wave] * A;
#pragma unroll
        for (int off = 1; off < 64; off <<= 1) {
            float t2 = __shfl_up(s, off);
            if (lane >= off) s += t2;
        }
        eA[wave][lane] = expneg_(s);
    }
    // stage Yd: 2048 short8, 4 per thread
#pragma unroll
    for (int i = 0; i < 4; ++i) {
        int u = tid + 512 * i;
        int r = u >> 5, g = u & 31;
        *(short8*)&Yz[r][g * 8] = *(const short8*)(Y + (rowbase + r) * DI_ + g * 8);
    }
    // C fragment in regs (A-operand), reused for both heads of this wave
    short8 afr[2];
#pragma unroll
    for (int ks = 0; ks < 2; ++ks)
        afr[ks] = *(const short8*)(XBC2 + (rowbase + 16 * strip + ln15) * DBC_
                                   + 64 + ks * 32 + q * 8);
    // write pr=0 Ps2 (heads 0,1) from prefetched regs — covered by B1
#pragma unroll
    for (int i = 0; i < 2; ++i) {
        int u = tid + 512 * i;
        int hh = u >> 9, r = (u >> 3) & 63, g = u & 7;
        *(short8*)&Ps2[hh][r][g * 8] = stq[i];
    }
    __syncthreads();   // B1: Yz, eA, Ps2(h0,h1) ready

    // head pairs: group 0-3 -> head 2*pr, group 4-7 -> head 2*pr+1
    for (int pr = 0; pr < 2; ++pr) {
        const int h = 2 * pr + grp;
        f32x4 a2[4];
#pragma unroll
        for (int ct = 0; ct < 4; ++ct) a2[ct] = (f32x4){0.f, 0.f, 0.f, 0.f};
#pragma unroll
        for (int ks = 0; ks < 2; ++ks)
#pragma unroll
            for (int ct = 0; ct < 4; ++ct) {
                short8 bfr = *(const short8*)&Ps2[grp][16 * ct + ln15][ks * 32 + q * 8];
                a2[ct] = __builtin_amdgcn_mfma_f32_16x16x32_bf16(afr[ks], bfr, a2[ct], 0, 0, 0);
            }
#pragma unroll
        for (int ct = 0; ct < 4; ++ct)
#pragma unroll
            for (int rg = 0; rg < 4; ++rg) {
                int l = 16 * strip + 4 * q + rg, p = 16 * ct + ln15;
                float yv = bs2f(Yz[l][h * 64 + p]) + a2[ct][rg] * eA[h][l];
                Yz[l][h * 64 + p] = f2bs(yv);   // disjoint (l, h-cols) per wave
            }
        if (pr == 0) {
            __syncthreads();   // B2: pr0 Ps2 consumers done
            // write pr=1 Ps2 (heads 2,3) from prefetched regs
#pragma unroll
            for (int i = 0; i < 2; ++i) {
                int u = tid + 512 * (i + 2);
                int hh = (u >> 9) - 2, r = (u >> 3) & 63, g = u & 7;
                *(short8*)&Ps2[hh][r][g * 8] = stq[i + 2];
            }
            __syncthreads();   // B3: pr1 Ps2 ready
        }
    }
    __syncthreads();   // B4: all Yz head-updates visible

    // gate + RMSNorm: wave rows 8*wave .. 8*wave+7 (wave-private)
    float nwv[4];
#pragma unroll
    for (int j = 0; j < 4; ++j) nwv[j] = nw[lane * 4 + j];
#pragma unroll
    for (int rr = 0; rr < 8; ++rr) {
        int row = 8 * wave + rr;
        S4 zv4 = *(const S4*)(Z + (rowbase + row) * DI_ + lane * 4);
        short zr[4] = { zv4.a, zv4.b, zv4.c, zv4.d };
        float v[4]; float ss = 0.f;
#pragma unroll
        for (int j = 0; j < 4; ++j) {
            float yv = bs2f(Yz[row][lane * 4 + j]);
            float zf = bs2f(zr[j]);
            v[j] = yv * zf * sigmoidf_(zf);
            ss += v[j] * v[j];
        }
#pragma unroll
        for (int off = 1; off < 64; off <<= 1) ss += __shfl_xor(ss, off);
        float rn = rsqrtf(ss * (1.f / 256.f) + 1e-5f);
#pragma unroll
        for (int j = 0; j < 4; ++j)
            Yz[row][lane * 4 + j] = f2bs(v[j] * rn * nwv[j]);
    }
    __syncthreads();   // B5: final Yz visible to all waves

    // out-projection; wave = (strip, Nhalf=grp); dir1 row-reversed
    const int prow = 16 * strip + ln15;
    const int lr = d ? 63 - prow : prow;
    short8 wf[4], wfn[4];
#pragma unroll
    for (int ct = 0; ct < 4; ++ct)
        wf[ct] = *(const short8*)(Wo + (size_t)(16 * (4 * grp + ct) + ln15) * DI_ + q * 8);
#pragma unroll
    for (int it = 0; it < 8; ++it) {
        const int k0 = (it >> 1) * 64 + (it & 1) * 32;
        if (it < 7) {
            const int k0n = ((it + 1) >> 1) * 64 + ((it + 1) & 1) * 32;
#pragma unroll
            for (int ct = 0; ct < 4; ++ct)
                wfn[ct] = *(const short8*)(Wo + (size_t)(16 * (4 * grp + ct) + ln15) * DI_
                                           + k0n + q * 8);
        }
        short8 afr2 = *(const short8*)&Yz[lr][k0 + q * 8];
#pragma unroll
        for (int ct = 0; ct < 4; ++ct)
            acc[ct] = __builtin_amdgcn_mfma_f32_16x16x32_bf16(afr2, wf[ct], acc[ct], 0, 0, 0);
#pragma unroll
        for (int ct = 0; ct < 4; ++ct) wf[ct] = wfn[ct];
    }

    // write this dir's partial (f32) at physical coordinates
#pragma unroll
    for (int ct = 0; ct < 4; ++ct)
#pragma unroll
        for (int rg = 0; rg < 4; ++rg) {
            int row = 16 * strip + 4 * q + rg, col = 16 * (4 * grp + ct) + ln15;
            outp[((size_t)(pt0 + row)) * DM_ + col] = acc[ct][rg];
        }
}

// ---------------------------------------------------------------------------
// K5: out += Obuf (f32, float4-vectorized). T_*DM_/4 = 1,048,576 float4.
// grid 4096, block 256, one float4 per thread.
// ---------------------------------------------------------------------------
__global__ __launch_bounds__(256) void k_addout(float* __restrict__ out,
                                                const float* __restrict__ Obuf)
{
    const int gid = blockIdx.x * 256 + threadIdx.x;
    float4 a = ((const float4*)out)[gid];
    float4 b = ((const float4*)Obuf)[gid];
    a.x += b.x; a.y += b.y; a.z += b.z; a.w += b.w;
    ((float4*)out)[gid] = a;
}

// ---------------------------------------------------------------------------
extern "C" void kernel_launch(void* const* d_in, const int* in_sizes, int n_in,
                              void* d_out, int out_size, void* d_ws, size_t ws_size,
                              hipStream_t stream)
{
    const float* x    = (const float*)d_in[0];
    const float* WiF  = (const float*)d_in[1];
    const float* cwF  = (const float*)d_in[2];
    const float* cbF  = (const float*)d_in[3];
    const float* dtbF = (const float*)d_in[4];
    const float* AlF  = (const float*)d_in[5];
    const float* DpF  = (const float*)d_in[6];
    const float* nwF  = (const float*)d_in[7];
    const float* WoF  = (const float*)d_in[8];
    const float* WiB  = (const float*)d_in[9];
    const float* cwB  = (const float*)d_in[10];
    const float* cbB  = (const float*)d_in[11];
    const float* dtbB = (const float*)d_in[12];
    const float* AlB  = (const float*)d_in[13];
    const float* DpB  = (const float*)d_in[14];
    const float* nwB  = (const float*)d_in[15];
    const float* WoB  = (const float*)d_in[16];

    const size_t nZ    = (size_t)2 * T_ * DI_;       // bf16
    const size_t nXBC2 = (size_t)2 * T_ * DBC_;      // bf16 (C only, stride 128)
    const size_t nY    = (size_t)2 * T_ * DI_;       // bf16 (Yd)
    const size_t nST   = (size_t)2 * B_ * NC_ * NH_ * HD_ * DS_;  // bf16
    const size_t nWb   = (size_t)2 * NWI + 2 * NWO;  // bf16 weight copies
    const size_t nDTV  = (size_t)2 * T_ * NH_;       // f32
    const size_t nCD   = (size_t)2 * B_ * NH_ * NC_; // f32
    const size_t nOb   = (size_t)T_ * DM_;           // f32 dir1 partial out
    const size_t need = (nZ + nXBC2 + nY + nST + nWb) * sizeof(bf16)
                      + (nDTV + nCD + nOb) * sizeof(float);
    if (ws_size < need) return;

    char* p = (char*)d_ws;
    bf16* Z    = (bf16*)p;            p += nZ * sizeof(bf16);
    bf16* XBC2 = (bf16*)p;            p += nXBC2 * sizeof(bf16);
    bf16* Yb   = (bf16*)p;            p += nY * sizeof(bf16);
    bf16* ST   = (bf16*)p;            p += nST * sizeof(bf16);
    bf16* WiFb = (bf16*)p;            p += (size_t)NWI * sizeof(bf16);
    bf16* WiBb = (bf16*)p;            p += (size_t)NWI * sizeof(bf16);
    bf16* WoFb = (bf16*)p;            p += (size_t)NWO * sizeof(bf16);
    bf16* WoBb = (bf16*)p;            p += (size_t)NWO * sizeof(bf16);
    float* DTV = (float*)p;           p += nDTV * sizeof(float);
    float* CDb = (float*)p;           p += nCD * sizeof(float);
    float* Obuf = (float*)p;

    k_prep<<<128, 256, 0, stream>>>(WiF, WiB, WoF, WoB, WiFb, WiBb, WoFb, WoBb);
    k_front_fused<<<dim3(512, 2), 256, 0, stream>>>(x, WiFb, WiBb, cwF, cbF, cwB, cbB,
                                                    dtbF, dtbB, AlF, AlB, DpF, DpB,
                                                    Z, XBC2, DTV, Yb, ST, CDb);
    k_scan<<<dim3(256, 2), 256, 0, stream>>>(ST, CDb);
    k_tail_fused<<<dim3(NC_, B_, 2), 512, 0, stream>>>(XBC2, DTV, AlF, AlB, ST, Z,
                                                       nwF, nwB, Yb, WoFb, WoBb,
                                                       (float*)d_out, Obuf);
    k_addout<<<4096, 256, 0, stream>>>((float*)d_out, Obuf);
}